// Round 4
// baseline (319.419 us; speedup 1.0000x reference)
//
#include <hip/hip_runtime.h>
#include <math.h>

// Problem constants
#define Bc   4
#define Hc   64
#define Wc   64
#define Dc   384
#define Nc   4096      // H*W
#define Mc   12
#define Pc   9
#define DHc  32
#define DFFc 1152
#define BNc  (Bc*Nc)   // 16384

typedef __attribute__((ext_vector_type(8))) short short8;
typedef __attribute__((ext_vector_type(4))) float floatx4;

__device__ __forceinline__ ushort f2bf(float f) {
    union { float f; unsigned u; } v; v.f = f;
    unsigned r = v.u + 0x7fffu + ((v.u >> 16) & 1u);   // RNE
    return (ushort)(r >> 16);
}
__device__ __forceinline__ float bf2f(ushort u) {
    union { unsigned u; float f; } v; v.u = (unsigned)u << 16; return v.f;
}

__device__ __forceinline__ void gload_lds16(const void* g, void* l) {
    __builtin_amdgcn_global_load_lds(
        (const __attribute__((address_space(1))) void*)(uintptr_t)g,
        (__attribute__((address_space(3))) void*)(uintptr_t)l,
        16, 0, 0);
}

// ---------------------------------------------------------------------------
// K0: fused init — weight fp32->bf16 convert, bias concat, mask cumsums
// ---------------------------------------------------------------------------
#define SOW_N  82944     // 216*384
#define AWW_N  41472     // 108*384
#define VPW_N  147456    // 384*384
#define OPW_N  147456
#define W1_N   442368    // 1152*384
#define W2_N   442368    // 384*1152
#define WTOT   1304064

__global__ void init_kernel(const float* __restrict__ so_w,
                            const float* __restrict__ aw_w,
                            const float* __restrict__ vp_w,
                            const float* __restrict__ op_w,
                            const float* __restrict__ w1,
                            const float* __restrict__ w2,
                            const float* __restrict__ so_b,
                            const float* __restrict__ aw_b,
                            const float* __restrict__ qmask,
                            ushort* __restrict__ out,
                            float* __restrict__ bias_out,
                            float* __restrict__ cum_y,
                            float* __restrict__ cum_x) {
    int i = blockIdx.x * 256 + threadIdx.x;
    if (i < WTOT) {
        float v;
        int j = i;
        if (j < SOW_N) v = so_w[j];
        else if ((j -= SOW_N) < AWW_N) v = aw_w[j];
        else if ((j -= AWW_N) < VPW_N) v = vp_w[j];
        else if ((j -= VPW_N) < OPW_N) v = op_w[j];
        else if ((j -= OPW_N) < W1_N)  v = w1[j];
        else { j -= W1_N; v = w2[j]; }
        out[i] = f2bf(v);
        return;
    }
    int j = i - WTOT;
    if (j < 384) {   // pad bias to 384 with zeros (col-tile over-read safety)
        bias_out[j] = (j < 216) ? so_b[j] : (j < 324 ? aw_b[j - 216] : 0.f);
        return;
    }
    int t = j - 384;
    if (t < Bc * Wc) {
        int b = t / Wc, w = t % Wc;
        float run = 0.f;
        for (int h = 0; h < Hc; ++h) {
            run += (qmask[(b * Hc + h) * Wc + w] == 255.0f) ? 0.f : 1.f;
            cum_y[(b * Hc + h) * Wc + w] = run;
        }
    } else if (t < Bc * Wc + Bc * Hc) {
        int t2 = t - Bc * Wc;
        int b = t2 / Hc, h = t2 % Hc;
        float run = 0.f;
        for (int w = 0; w < Wc; ++w) {
            run += (qmask[(b * Hc + h) * Wc + w] == 255.0f) ? 0.f : 1.f;
            cum_x[(b * Hc + h) * Wc + w] = run;
        }
    }
}

// ---------------------------------------------------------------------------
// K1: transpose x[B,D,N] -> src_bf[B,N,D] (bf16);
//     qpos_bf = bf16(src + sine_pos + level_embed). Fast-math trig.
// ---------------------------------------------------------------------------
__global__ void transpose_pos_kernel(const float* __restrict__ x,
                                     const float* __restrict__ cum_y,
                                     const float* __restrict__ cum_x,
                                     const float* __restrict__ level_embed,
                                     ushort* __restrict__ src_bf,
                                     ushort* __restrict__ qpos_bf) {
    __shared__ float tile[32][33];
    int b  = blockIdx.z;
    int n0 = blockIdx.x * 32, d0 = blockIdx.y * 32;
    int tx = threadIdx.x, ty = threadIdx.y;
    tile[ty][tx] = x[((size_t)b * Dc + (d0 + ty)) * Nc + (n0 + tx)];
    __syncthreads();
    int n = n0 + ty, d = d0 + tx;
    float v = tile[tx][ty];
    size_t oi = ((size_t)b * Nc + n) * Dc + d;
    src_bf[oi] = f2bf(v);
    int h = n >> 6, w = n & 63;
    const float TWO_PI = 6.28318530717958647692f;
    float vy = cum_y[(b * Hc + h) * Wc + w] /
               (cum_y[(b * Hc + (Hc - 1)) * Wc + w] + 1e-6f) * TWO_PI;
    float vx = cum_x[(b * Hc + h) * Wc + w] /
               (cum_x[(b * Hc + h) * Wc + (Wc - 1)] + 1e-6f) * TWO_PI;
    int   i  = (d < 192) ? d : d - 192;
    float vv = (d < 192) ? vy : vx;
    float e   = (float)(i >> 1) * (2.0f / 192.0f);
    float idt = exp2f(e * -13.28771237954945f);
    float ang = vv * idt;
    float pe  = (i & 1) ? __cosf(ang) : __sinf(ang);
    qpos_bf[oi] = f2bf(v + pe + level_embed[d]);
}

// ---------------------------------------------------------------------------
// K2: bf16 MFMA GEMM core (R8/R9-verified): 128x128 tile, global_load_lds,
//     double-buffered LDS, one barrier/K-chunk, row-fast grid for XCD L2.
// ---------------------------------------------------------------------------
template <int KT>
__device__ __forceinline__ void gemm_core(
        const ushort* __restrict__ A, const ushort* __restrict__ Wt,
        const float* __restrict__ bias,
        float* __restrict__ Cf, ushort* __restrict__ Cb,
        int Nout, int relu, const float* __restrict__ qmask,
        ushort* As, ushort* Bs) {           // As/Bs: 2 x 128*32 each
    constexpr int NCH = KT / 32;
    const int tid  = threadIdx.x;
    const int m0   = blockIdx.x * 128;
    const int n0   = blockIdx.y * 128;
    const int lane = tid & 63;
    const int wv   = tid >> 6;
    const int wr   = (wv >> 1) * 64;
    const int wc   = (wv & 1) * 64;
    const int quad = lane >> 4;
    const int lrow = lane & 15;
    const int srow = wv * 32 + (lane >> 2);
    const int scol = (lane & 3) * 8;

    floatx4 acc[4][4];
    #pragma unroll
    for (int i = 0; i < 4; ++i)
        #pragma unroll
        for (int j = 0; j < 4; ++j)
            acc[i][j] = (floatx4)(0.f);

    #pragma unroll
    for (int s = 0; s < 2; ++s) {
        gload_lds16(A  + (size_t)(m0 + srow + s * 16) * KT + scol,
                    As + wv * 1024 + s * 512);
        gload_lds16(Wt + (size_t)(n0 + srow + s * 16) * KT + scol,
                    Bs + wv * 1024 + s * 512);
    }

    for (int c = 0; c < NCH; ++c) {
        const int cur = c & 1;
        __syncthreads();
        if (c + 1 < NCH) {
            const int k0 = (c + 1) * 32;
            #pragma unroll
            for (int s = 0; s < 2; ++s) {
                gload_lds16(A  + (size_t)(m0 + srow + s * 16) * KT + k0 + scol,
                            As + (cur ^ 1) * 4096 + wv * 1024 + s * 512);
                gload_lds16(Wt + (size_t)(n0 + srow + s * 16) * KT + k0 + scol,
                            Bs + (cur ^ 1) * 4096 + wv * 1024 + s * 512);
            }
        }
        short8 afr[4], bfr[4];
        #pragma unroll
        for (int i = 0; i < 4; ++i)
            afr[i] = *(const short8*)(As + cur * 4096 +
                                      (wr + i * 16 + lrow) * 32 + quad * 8);
        #pragma unroll
        for (int j = 0; j < 4; ++j)
            bfr[j] = *(const short8*)(Bs + cur * 4096 +
                                      (wc + j * 16 + lrow) * 32 + quad * 8);
        #pragma unroll
        for (int i = 0; i < 4; ++i)
            #pragma unroll
            for (int j = 0; j < 4; ++j)
                acc[i][j] = __builtin_amdgcn_mfma_f32_16x16x32_bf16(
                    afr[i], bfr[j], acc[i][j], 0, 0, 0);
    }

    float mz[4][4];
    #pragma unroll
    for (int i = 0; i < 4; ++i)
        #pragma unroll
        for (int r = 0; r < 4; ++r) {
            int row = m0 + wr + i * 16 + quad * 4 + r;
            mz[i][r] = (qmask && qmask[row] == 255.0f) ? 0.f : 1.f;
        }

    #pragma unroll
    for (int i = 0; i < 4; ++i) {
        #pragma unroll
        for (int j = 0; j < 4; ++j) {
            int col = n0 + wc + j * 16 + lrow;
            if (col >= Nout) continue;
            float bsv = bias ? bias[col] : 0.f;
            #pragma unroll
            for (int r = 0; r < 4; ++r) {
                int row = m0 + wr + i * 16 + quad * 4 + r;
                float v = acc[i][j][r] + bsv;
                if (relu) v = fmaxf(v, 0.f);
                v *= mz[i][r];
                if (Cf) Cf[(size_t)row * Nout + col] = v;
                if (Cb) Cb[(size_t)row * Nout + col] = f2bf(v);
            }
        }
    }
}

template <int KT>
__global__ __launch_bounds__(256) void gemm_single_kernel(
        const ushort* __restrict__ A, const ushort* __restrict__ Wt,
        const float* __restrict__ bias,
        float* __restrict__ Cf, ushort* __restrict__ Cb,
        int Nout, int relu, const float* __restrict__ qmask) {
    __shared__ ushort As[2 * 128 * 32];
    __shared__ ushort Bs[2 * 128 * 32];
    gemm_core<KT>(A, Wt, bias, Cf, Cb, Nout, relu, qmask, As, Bs);
}

// dual dispatch: z=0 -> soaw projection, z=1 -> value projection (overlapped)
__global__ __launch_bounds__(256) void gemm_dual_kernel(
        const ushort* __restrict__ A0, const ushort* __restrict__ W0,
        const float* __restrict__ b0, float* __restrict__ Cf0,
        const ushort* __restrict__ A1, const ushort* __restrict__ W1,
        const float* __restrict__ b1, ushort* __restrict__ Cb1,
        const float* __restrict__ qmask) {
    __shared__ ushort As[2 * 128 * 32];
    __shared__ ushort Bs[2 * 128 * 32];
    if (blockIdx.z == 0)
        gemm_core<384>(A0, W0, b0, Cf0, nullptr, 384, 0, nullptr, As, Bs);
    else
        gemm_core<384>(A1, W1, b1, nullptr, Cb1, 384, 0, qmask, As, Bs);
}

// ---------------------------------------------------------------------------
// K3: full-row GEMM + LayerNorm fusion — ASYNC wave-private K-loop, DEPTH-3.
//     Grid 256 (64-row stripe), 512 threads (8 waves), 1 block/CU.
//     NO __syncthreads in the K-loop. Per-wave FIFO (issue order fixed by
//     asm "memory" clobbers):
//       prologue: A0(4) S0(3) A1(4) S1(3) A2(4)            -> 18 outstanding
//       iter c:   wait vmcnt(11)   [completes A(c)+S(c), issued 2-3 iters ago]
//                 STAGE_W(c+2) -> LDS ring-3 (wave-private, no barrier)
//                 LOAD_A(c+3)  -> register ring-4 (static idx, full unroll)
//                 12 MFMA on A(c) regs + S(c) LDS
//       tail:     waits 11 / 7 / 0 for the last three chunks.
//     Coverage: waits target loads issued >=2 chunks (~500+ cy) earlier,
//     >= L2/L3 latency — this fixes R3's depth-1 A-wait stall.
//     Epilogue (R0-verified math): t = acc + bias + residual; row sums via
//     shfl_xor(16) + 8-wave LDS combine -> LN.
//     MODE 0: residual bf16 (src), write q1_f (fp32) + q1_bf (bf16).
//     MODE 1: residual fp32 (q1), write transposed fp32 out[b,d,n] via
//             padded LDS tile (stride 193) overlaid on Bs, 2 col-halves.
// ---------------------------------------------------------------------------
template <int KT, int MODE>
__global__ __launch_bounds__(512, 2) void gemm_fullrow_kernel(
        const ushort* __restrict__ A, const ushort* __restrict__ Wt,
        const float* __restrict__ bias, const void* __restrict__ resid,
        const float* __restrict__ g, const float* __restrict__ beta,
        float* __restrict__ outf, ushort* __restrict__ outb) {
    constexpr int NCH = KT / 32;
    __shared__ ushort Bs[8 * 3 * 1536];       // 72KB: per-wave 3 bufs x 48x32
    __shared__ float eps1[8][64], eps2[8][64];
    __shared__ float mu_l[64], rs_l[64];
    const int tid  = threadIdx.x;
    const int lane = tid & 63;
    const int wv   = tid >> 6;                // 0..7
    const int quad = lane >> 4;
    const int lrow = lane & 15;
    const int m0   = blockIdx.x * 64;
    const int srow = lane >> 2;               // 0..15
    const int scol = (lane & 3) * 8;

    ushort* BsW = Bs + wv * (3 * 1536);
    const ushort* wsrc  = Wt + (size_t)(wv * 48 + srow) * KT + scol;
    const ushort* abase = A  + (size_t)(m0 + lrow) * KT + quad * 8;

    floatx4 acc[4][3];
    #pragma unroll
    for (int i = 0; i < 4; ++i)
        #pragma unroll
        for (int j = 0; j < 3; ++j)
            acc[i][j] = (floatx4)(0.f);

#define STAGE_W(c, buf)                                                      \
    gload_lds16(wsrc + (size_t)0 * 16 * KT + (c) * 32, BsW + (buf) * 1536);  \
    gload_lds16(wsrc + (size_t)1 * 16 * KT + (c) * 32, BsW + (buf) * 1536 + 512); \
    gload_lds16(wsrc + (size_t)2 * 16 * KT + (c) * 32, BsW + (buf) * 1536 + 1024);

#define LOAD_A(slot, c)                                                      \
    afr[slot][0] = *(const short8*)(abase + (size_t)0 * 16 * KT + (c) * 32); \
    afr[slot][1] = *(const short8*)(abase + (size_t)1 * 16 * KT + (c) * 32); \
    afr[slot][2] = *(const short8*)(abase + (size_t)2 * 16 * KT + (c) * 32); \
    afr[slot][3] = *(const short8*)(abase + (size_t)3 * 16 * KT + (c) * 32);

#define DO_MFMA(slot, buf)                                                   \
    {   short8 bfr[3];                                                       \
        bfr[0] = *(const short8*)(BsW + (buf) * 1536 + (lrow)      * 32 + quad * 8); \
        bfr[1] = *(const short8*)(BsW + (buf) * 1536 + (16 + lrow) * 32 + quad * 8); \
        bfr[2] = *(const short8*)(BsW + (buf) * 1536 + (32 + lrow) * 32 + quad * 8); \
        _Pragma("unroll")                                                    \
        for (int i_ = 0; i_ < 4; ++i_) {                                     \
            acc[i_][0] = __builtin_amdgcn_mfma_f32_16x16x32_bf16(afr[slot][i_], bfr[0], acc[i_][0], 0, 0, 0); \
            acc[i_][1] = __builtin_amdgcn_mfma_f32_16x16x32_bf16(afr[slot][i_], bfr[1], acc[i_][1], 0, 0, 0); \
            acc[i_][2] = __builtin_amdgcn_mfma_f32_16x16x32_bf16(afr[slot][i_], bfr[2], acc[i_][2], 0, 0, 0); \
        } }

    short8 afr[4][4];
    // prologue FIFO: A0(4) S0(3) A1(4) S1(3) A2(4) -> 18 outstanding
    LOAD_A(0, 0)
    STAGE_W(0, 0)
    LOAD_A(1, 1)
    STAGE_W(1, 1)
    LOAD_A(2, 2)

    #pragma unroll
    for (int c = 0; c <= NCH - 3; ++c) {
        // completes A(c)+S(c); leaves A(c+1),S(c+1),A(c+2) (and grows below)
        asm volatile("s_waitcnt vmcnt(11)" ::: "memory");
        STAGE_W(c + 2, (c + 2) % 3)
        if (c + 3 < NCH) { LOAD_A((c + 3) % 4, c + 3) }
        DO_MFMA(c % 4, c % 3)
    }
    asm volatile("s_waitcnt vmcnt(7)" ::: "memory");
    DO_MFMA((NCH - 2) % 4, (NCH - 2) % 3)
    asm volatile("s_waitcnt vmcnt(0)" ::: "memory");
    DO_MFMA((NCH - 1) % 4, (NCH - 1) % 3)

#undef STAGE_W
#undef LOAD_A
#undef DO_MFMA

    // --- epilogue: residual add + row-sum (R0-verified) ---
    float s1[16], s2[16];
    #pragma unroll
    for (int k = 0; k < 16; ++k) { s1[k] = 0.f; s2[k] = 0.f; }
    #pragma unroll
    for (int i = 0; i < 4; ++i) {
        #pragma unroll
        for (int r = 0; r < 4; ++r) {
            int rl = i * 16 + quad * 4 + r;
            #pragma unroll
            for (int j = 0; j < 3; ++j) {
                int col = wv * 48 + j * 16 + lrow;
                float t = acc[i][j][r];
                if (bias) t += bias[col];
                if (MODE == 0)
                    t += bf2f(((const ushort*)resid)[(size_t)(m0 + rl) * Dc + col]);
                else
                    t += ((const float*)resid)[(size_t)(m0 + rl) * Dc + col];
                acc[i][j][r] = t;
                s1[i * 4 + r] += t;
                s2[i * 4 + r] += t * t;
            }
        }
    }
    // reduce over the 16 lrow lanes (bits 0..3 of lane id)
    #pragma unroll
    for (int mm = 1; mm < 16; mm <<= 1) {
        #pragma unroll
        for (int k = 0; k < 16; ++k) {
            s1[k] += __shfl_xor(s1[k], mm);
            s2[k] += __shfl_xor(s2[k], mm);
        }
    }
    if (lrow == 0) {
        #pragma unroll
        for (int i = 0; i < 4; ++i)
            #pragma unroll
            for (int r = 0; r < 4; ++r) {
                int rl = i * 16 + quad * 4 + r;
                eps1[wv][rl] = s1[i * 4 + r];
                eps2[wv][rl] = s2[i * 4 + r];
            }
    }
    __syncthreads();
    if (tid < 64) {
        float a1 = 0.f, a2 = 0.f;
        #pragma unroll
        for (int w = 0; w < 8; ++w) { a1 += eps1[w][tid]; a2 += eps2[w][tid]; }
        float mu  = a1 * (1.0f / Dc);
        float var = a2 * (1.0f / Dc) - mu * mu;
        mu_l[tid] = mu;
        rs_l[tid] = rsqrtf(var + 1e-5f);
    }
    __syncthreads();

    // normalize in place
    #pragma unroll
    for (int i = 0; i < 4; ++i) {
        #pragma unroll
        for (int r = 0; r < 4; ++r) {
            int rl = i * 16 + quad * 4 + r;
            float mu = mu_l[rl], rs = rs_l[rl];
            #pragma unroll
            for (int j = 0; j < 3; ++j) {
                int col = wv * 48 + j * 16 + lrow;
                acc[i][j][r] = (acc[i][j][r] - mu) * rs * g[col] + beta[col];
            }
        }
    }

    if (MODE == 0) {
        #pragma unroll
        for (int i = 0; i < 4; ++i)
            #pragma unroll
            for (int j = 0; j < 3; ++j) {
                int col = wv * 48 + j * 16 + lrow;
                #pragma unroll
                for (int r = 0; r < 4; ++r) {
                    int rl = i * 16 + quad * 4 + r;
                    float v = acc[i][j][r];
                    outf[(size_t)(m0 + rl) * Dc + col] = v;
                    outb[(size_t)(m0 + rl) * Dc + col] = f2bf(v);
                }
            }
    } else {
        // transposed write via LDS tile (64 rows x 192 cols, stride 193)
        float* tile = (float*)Bs;
        const int b   = m0 >> 12;
        const int n0r = m0 & 4095;
        #pragma unroll
        for (int gp = 0; gp < 2; ++gp) {
            __syncthreads();                  // tile free / prev pass done
            if ((wv >> 2) == gp) {
                int cbase = (wv & 3) * 48;
                #pragma unroll
                for (int i = 0; i < 4; ++i)
                    #pragma unroll
                    for (int j = 0; j < 3; ++j) {
                        int c = cbase + j * 16 + lrow;
                        #pragma unroll
                        for (int r = 0; r < 4; ++r) {
                            int rl = i * 16 + quad * 4 + r;
                            tile[rl * 193 + c] = acc[i][j][r];
                        }
                    }
            }
            __syncthreads();
            const int row = tid & 63;
            const int cp  = tid >> 6;         // 0..7
            #pragma unroll
            for (int it = 0; it < 24; ++it) {
                int c = it * 8 + cp;
                outf[((size_t)(b * Dc + gp * 192 + c)) * Nc + n0r + row] =
                    tile[row * 193 + c];
            }
        }
    }
}

// ---------------------------------------------------------------------------
// K4: deformable attention gather (softmax fused).
//     Slice-major mapping: one block = one (b,m) value slice x one image row h
//     (64 consecutive n). Sampling taps cluster in ~5 rows of ONE 256KB slice
//     (~20KB footprint -> L1-resident). bid = chunk*48 + slice with 48%8==0
//     -> all 64 blocks of a slice share bid%8 (same XCD) -> slice L2-resident.
// ---------------------------------------------------------------------------
__global__ __launch_bounds__(256) void deform_attn_kernel(
        const ushort* __restrict__ value_bf, const float* __restrict__ soaw,
        ushort* __restrict__ out) {
    int bid   = blockIdx.x;                            // 0..3071 = 64 chunks * 48 slices
    int slice = bid % 48;                              // b*M + m  (same-XCD per slice)
    int h     = bid / 48;                              // image row
    int m  = slice % Mc;
    int b  = slice / Mc;
    int w  = threadIdx.x >> 2;                         // 0..63 (column)
    int l4 = threadIdx.x & 3;                          // channel octet
    int n  = (h << 6) | w;
    int bn = b * Nc + n;
    const float* sop = soaw + (size_t)bn * 384 + m * 18;
    const float* lgt = soaw + (size_t)bn * 384 + 216 + m * Pc;
    float awv[Pc];
    float mx = lgt[0];
    #pragma unroll
    for (int i = 1; i < Pc; ++i) mx = fmaxf(mx, lgt[i]);
    float ssum = 0.f;
    #pragma unroll
    for (int i = 0; i < Pc; ++i) { awv[i] = __expf(lgt[i] - mx); ssum += awv[i]; }
    float sinv = 1.f / ssum;
    const ushort* vb = value_bf + ((size_t)b * Nc) * Dc + m * DHc + l4 * 8;
    float acc[8] = {0.f, 0.f, 0.f, 0.f, 0.f, 0.f, 0.f, 0.f};
    #pragma unroll
    for (int p = 0; p < Pc; ++p) {
        float2 so2 = *(const float2*)(sop + p * 2);
        float px = (float)w + so2.x;
        float py = (float)h + so2.y;
        float x0f = floorf(px), y0f = floorf(py);
        float lx = px - x0f, ly = py - y0f;
        int x0 = (int)x0f, y0 = (int)y0f;
        int x1 = x0 + 1,  y1 = y0 + 1;
        float a = awv[p] * sinv;
        float w00 = (1.f - lx) * (1.f - ly) * a;
        float w01 = lx * (1.f - ly) * a;
        float w10 = (1.f - lx) * ly * a;
        float w11 = lx * ly * a;
        bool bx0 = (unsigned)x0 < 64u, bx1 = (unsigned)x1 < 64u;
        bool by0 = (unsigned)y0 < 64u, by1 = (unsigned)y1 < 64u;
        w00 = (bx0 && by0) ? w00 : 0.f;
        w01 = (bx1 && by0) ? w01 : 0.f;
        w10 = (bx0 && by1) ? w10 : 0.f;
        w11 = (bx1 && by1) ? w11 : 0.f;
        int cx0 = min(max(x0, 0), 63), cx1 = min(max(x1, 0), 63);
        int cy0 = min(max(y0, 0), 63), cy1 = min(max(y1, 0), 63);
        uint4 q00 = *(const uint4*)(vb + (size_t)(cy0 * 64 + cx0) * Dc);
        uint4 q01 = *(const uint4*)(vb + (size_t)(cy0 * 64 + cx1) * Dc);
        uint4 q10 = *(const uint4*)(vb + (size_t)(cy1 * 64 + cx0) * Dc);
        uint4 q11 = *(const uint4*)(vb + (size_t)(cy1 * 64 + cx1) * Dc);
        union { unsigned u; float f; } t;
        #define ACC2(word, wg, k)                                   \
            t.u = (word) << 16;         acc[k]     += (wg) * t.f;   \
            t.u = (word) & 0xffff0000u; acc[k + 1] += (wg) * t.f;
        #define ACC8(q, wg) \
            ACC2((q).x, wg, 0) ACC2((q).y, wg, 2) ACC2((q).z, wg, 4) ACC2((q).w, wg, 6)
        ACC8(q00, w00) ACC8(q01, w01) ACC8(q10, w10) ACC8(q11, w11)
        #undef ACC8
        #undef ACC2
    }
    short8 o;
    #pragma unroll
    for (int k = 0; k < 8; ++k) o[k] = (short)f2bf(acc[k]);
    *(short8*)(out + (size_t)bn * Dc + m * DHc + l4 * 8) = o;
}

// ---------------------------------------------------------------------------
extern "C" void kernel_launch(void* const* d_in, const int* in_sizes, int n_in,
                              void* d_out, int out_size, void* d_ws, size_t ws_size,
                              hipStream_t stream) {
    (void)in_sizes; (void)n_in; (void)out_size; (void)ws_size;
    const float* x      = (const float*)d_in[0];
    const float* qmask  = (const float*)d_in[1];
    const float* so_w   = (const float*)d_in[2];
    const float* so_b   = (const float*)d_in[3];
    const float* aw_w   = (const float*)d_in[4];
    const float* aw_b   = (const float*)d_in[5];
    const float* vp_w   = (const float*)d_in[6];
    const float* vp_b   = (const float*)d_in[7];
    const float* op_w   = (const float*)d_in[8];
    const float* op_b   = (const float*)d_in[9];
    const float* ln1_g  = (const float*)d_in[10];
    const float* ln1_b  = (const float*)d_in[11];
    const float* w1     = (const float*)d_in[12];
    const float* w2     = (const float*)d_in[13];
    const float* ln2_g  = (const float*)d_in[14];
    const float* ln2_b  = (const float*)d_in[15];
    const float* lvl    = (const float*)d_in[16];
    float* out = (float*)d_out;

    // Workspace (~104 MB):
    float*  ws       = (float*)d_ws;
    float*  q1_f     = ws;                          // 6291456 f (LN1 out / LN2 residual)
    ushort* src_bf   = (ushort*)(q1_f + 6291456);   // 6291456 us
    ushort* qpos_bf  = src_bf + 6291456;            // 6291456 us (qpos->attn->q1_bf)
    ushort* value_bf = qpos_bf + 6291456;           // 6291456 us
    ushort* hbuf_bf  = value_bf + 6291456;          // 18874368 us (FFN hidden)
    float*  soaw_f   = (float*)hbuf_bf;             // 6291456 f overlay (dead pre-FFN1)
    ushort* wbuf     = hbuf_bf + 18874368;          // 1304064 us
    float*  soaw_bias= (float*)(wbuf + 1304064);    // 384 f (padded)
    float*  cum_y    = soaw_bias + 384;             // 16384 f
    float*  cum_x    = cum_y + 16384;               // 16384 f

    const ushort* soaw_wb = wbuf;                   // [324,384] (so_w ++ aw_w)
    const ushort* vp_wb = soaw_wb + SOW_N + AWW_N;
    const ushort* op_wb = vp_wb + VPW_N;
    const ushort* w1_b  = op_wb + OPW_N;
    const ushort* w2_b  = w1_b + W1_N;

    // 0) fused init
    init_kernel<<<(WTOT + 384 + 512 + 255) / 256, 256, 0, stream>>>(
        so_w, aw_w, vp_w, op_w, w1, w2, so_b, aw_b, qmask,
        wbuf, soaw_bias, cum_y, cum_x);
    // 1) transpose + pos encode
    transpose_pos_kernel<<<dim3(Nc / 32, Dc / 32, Bc), dim3(32, 32), 0, stream>>>(
        x, cum_y, cum_x, lvl, src_bf, qpos_bf);
    // 2) DUAL: z=0 soaw projection (fp32 out), z=1 value projection (bf16+mask)
    gemm_dual_kernel<<<dim3(BNc / 128, 3, 2), 256, 0, stream>>>(
        qpos_bf, soaw_wb, soaw_bias, soaw_f,
        src_bf, vp_wb, vp_b, value_bf, qmask);
    // 3) deformable gather (softmax fused, slice-major) -> attn into qpos_bf
    deform_attn_kernel<<<3072, 256, 0, stream>>>(
        value_bf, soaw_f, qpos_bf);
    // 4) fused op-proj + residual(src_bf) + LN1 -> q1_f + q1_bf (in qpos_bf)
    gemm_fullrow_kernel<384, 0><<<BNc / 64, 512, 0, stream>>>(
        qpos_bf, op_wb, op_b, src_bf, ln1_g, ln1_b, q1_f, qpos_bf);
    // 5) FFN1 (relu, bf16 hidden)
    gemm_single_kernel<384><<<dim3(BNc / 128, 9), 256, 0, stream>>>(
        qpos_bf, w1_b, nullptr, nullptr, hbuf_bf, DFFc, 1, nullptr);
    // 6) fused FFN2 + residual(q1_f) + LN2 + transpose -> out[B,D,N]
    gemm_fullrow_kernel<1152, 1><<<BNc / 64, 512, 0, stream>>>(
        hbuf_bf, w2_b, nullptr, q1_f, ln2_g, ln2_b, out, nullptr);
}

// Round 5
// 269.740 us; speedup vs baseline: 1.1842x; 1.1842x over previous
//
#include <hip/hip_runtime.h>
#include <math.h>

// Problem constants
#define Bc   4
#define Hc   64
#define Wc   64
#define Dc   384
#define Nc   4096      // H*W
#define Mc   12
#define Pc   9
#define DHc  32
#define DFFc 1152
#define BNc  (Bc*Nc)   // 16384

typedef __attribute__((ext_vector_type(8))) short short8;
typedef __attribute__((ext_vector_type(4))) float floatx4;

__device__ __forceinline__ ushort f2bf(float f) {
    union { float f; unsigned u; } v; v.f = f;
    unsigned r = v.u + 0x7fffu + ((v.u >> 16) & 1u);   // RNE
    return (ushort)(r >> 16);
}
__device__ __forceinline__ float bf2f(ushort u) {
    union { unsigned u; float f; } v; v.u = (unsigned)u << 16; return v.f;
}

__device__ __forceinline__ void gload_lds16(const void* g, void* l) {
    __builtin_amdgcn_global_load_lds(
        (const __attribute__((address_space(1))) void*)(uintptr_t)g,
        (__attribute__((address_space(3))) void*)(uintptr_t)l,
        16, 0, 0);
}

// ---------------------------------------------------------------------------
// K0: fused init — weight fp32->bf16 convert, bias concat.
// ---------------------------------------------------------------------------
#define SOW_N  82944     // 216*384
#define AWW_N  41472     // 108*384
#define VPW_N  147456    // 384*384
#define OPW_N  147456
#define W1_N   442368    // 1152*384
#define W2_N   442368    // 384*1152
#define WTOT   1304064

__global__ void init_kernel(const float* __restrict__ so_w,
                            const float* __restrict__ aw_w,
                            const float* __restrict__ vp_w,
                            const float* __restrict__ op_w,
                            const float* __restrict__ w1,
                            const float* __restrict__ w2,
                            const float* __restrict__ so_b,
                            const float* __restrict__ aw_b,
                            ushort* __restrict__ out,
                            float* __restrict__ bias_out) {
    int i = blockIdx.x * 256 + threadIdx.x;
    if (i < WTOT) {
        float v;
        int j = i;
        if (j < SOW_N) v = so_w[j];
        else if ((j -= SOW_N) < AWW_N) v = aw_w[j];
        else if ((j -= AWW_N) < VPW_N) v = vp_w[j];
        else if ((j -= VPW_N) < OPW_N) v = op_w[j];
        else if ((j -= OPW_N) < W1_N)  v = w1[j];
        else { j -= W1_N; v = w2[j]; }
        out[i] = f2bf(v);
        return;
    }
    int j = i - WTOT;
    if (j < 384) {   // pad bias to 384 with zeros (col-tile over-read safety)
        bias_out[j] = (j < 216) ? so_b[j] : (j < 324 ? aw_b[j - 216] : 0.f);
    }
}

// ---------------------------------------------------------------------------
// K0b: mask cumsums via LDS (replaces 64-iteration serial global-latency
//      loops: scans run over a padded LDS tile, dumps are coalesced).
//      Same floating-point add order as before -> bitwise identical.
// ---------------------------------------------------------------------------
__global__ __launch_bounds__(256) void cumsum_kernel(
        const float* __restrict__ qmask,
        float* __restrict__ cum_y, float* __restrict__ cum_x) {
    __shared__ float nm[64 * 65];     // stride 65: conflict-free rows AND cols
    __shared__ float ot[64 * 65];
    int b = blockIdx.x;
    int t = threadIdx.x;
    const float* qm = qmask + b * 4096;
    #pragma unroll
    for (int k = 0; k < 16; ++k) {
        int idx = t + k * 256;
        nm[(idx >> 6) * 65 + (idx & 63)] = (qm[idx] == 255.0f) ? 0.f : 1.f;
    }
    __syncthreads();
    if (t < 64) {                     // column scan over h (cum_y), t = w
        float run = 0.f;
        for (int h = 0; h < 64; ++h) { run += nm[h * 65 + t]; ot[h * 65 + t] = run; }
    }
    __syncthreads();
    #pragma unroll
    for (int k = 0; k < 16; ++k) {
        int idx = t + k * 256;
        cum_y[b * 4096 + idx] = ot[(idx >> 6) * 65 + (idx & 63)];
    }
    __syncthreads();
    if (t < 64) {                     // row scan over w (cum_x), t = h
        float run = 0.f;
        for (int w = 0; w < 64; ++w) { run += nm[t * 65 + w]; ot[t * 65 + w] = run; }
    }
    __syncthreads();
    #pragma unroll
    for (int k = 0; k < 16; ++k) {
        int idx = t + k * 256;
        cum_x[b * 4096 + idx] = ot[(idx >> 6) * 65 + (idx & 63)];
    }
}

// ---------------------------------------------------------------------------
// K1: transpose x[B,D,N] -> src_bf[B,N,D] (bf16);
//     qpos_bf = bf16(src + sine_pos + level_embed). Fast-math trig.
// ---------------------------------------------------------------------------
__global__ void transpose_pos_kernel(const float* __restrict__ x,
                                     const float* __restrict__ cum_y,
                                     const float* __restrict__ cum_x,
                                     const float* __restrict__ level_embed,
                                     ushort* __restrict__ src_bf,
                                     ushort* __restrict__ qpos_bf) {
    __shared__ float tile[32][33];
    int b  = blockIdx.z;
    int n0 = blockIdx.x * 32, d0 = blockIdx.y * 32;
    int tx = threadIdx.x, ty = threadIdx.y;
    tile[ty][tx] = x[((size_t)b * Dc + (d0 + ty)) * Nc + (n0 + tx)];
    __syncthreads();
    int n = n0 + ty, d = d0 + tx;
    float v = tile[tx][ty];
    size_t oi = ((size_t)b * Nc + n) * Dc + d;
    src_bf[oi] = f2bf(v);
    int h = n >> 6, w = n & 63;
    const float TWO_PI = 6.28318530717958647692f;
    float vy = cum_y[(b * Hc + h) * Wc + w] /
               (cum_y[(b * Hc + (Hc - 1)) * Wc + w] + 1e-6f) * TWO_PI;
    float vx = cum_x[(b * Hc + h) * Wc + w] /
               (cum_x[(b * Hc + h) * Wc + (Wc - 1)] + 1e-6f) * TWO_PI;
    int   i  = (d < 192) ? d : d - 192;
    float vv = (d < 192) ? vy : vx;
    float e   = (float)(i >> 1) * (2.0f / 192.0f);
    float idt = exp2f(e * -13.28771237954945f);
    float ang = vv * idt;
    float pe  = (i & 1) ? __cosf(ang) : __sinf(ang);
    qpos_bf[oi] = f2bf(v + pe + level_embed[d]);
}

// ---------------------------------------------------------------------------
// K2: bf16 MFMA GEMM core (R8/R9-verified): 128x128 tile, global_load_lds,
//     double-buffered LDS, one barrier/K-chunk, row-fast grid for XCD L2.
// ---------------------------------------------------------------------------
template <int KT>
__device__ __forceinline__ void gemm_core(
        const ushort* __restrict__ A, const ushort* __restrict__ Wt,
        const float* __restrict__ bias,
        float* __restrict__ Cf, ushort* __restrict__ Cb,
        int Nout, int relu, const float* __restrict__ qmask,
        ushort* As, ushort* Bs) {           // As/Bs: 2 x 128*32 each
    constexpr int NCH = KT / 32;
    const int tid  = threadIdx.x;
    const int m0   = blockIdx.x * 128;
    const int n0   = blockIdx.y * 128;
    const int lane = tid & 63;
    const int wv   = tid >> 6;
    const int wr   = (wv >> 1) * 64;
    const int wc   = (wv & 1) * 64;
    const int quad = lane >> 4;
    const int lrow = lane & 15;
    const int srow = wv * 32 + (lane >> 2);
    const int scol = (lane & 3) * 8;

    floatx4 acc[4][4];
    #pragma unroll
    for (int i = 0; i < 4; ++i)
        #pragma unroll
        for (int j = 0; j < 4; ++j)
            acc[i][j] = (floatx4)(0.f);

    #pragma unroll
    for (int s = 0; s < 2; ++s) {
        gload_lds16(A  + (size_t)(m0 + srow + s * 16) * KT + scol,
                    As + wv * 1024 + s * 512);
        gload_lds16(Wt + (size_t)(n0 + srow + s * 16) * KT + scol,
                    Bs + wv * 1024 + s * 512);
    }

    for (int c = 0; c < NCH; ++c) {
        const int cur = c & 1;
        __syncthreads();
        if (c + 1 < NCH) {
            const int k0 = (c + 1) * 32;
            #pragma unroll
            for (int s = 0; s < 2; ++s) {
                gload_lds16(A  + (size_t)(m0 + srow + s * 16) * KT + k0 + scol,
                            As + (cur ^ 1) * 4096 + wv * 1024 + s * 512);
                gload_lds16(Wt + (size_t)(n0 + srow + s * 16) * KT + k0 + scol,
                            Bs + (cur ^ 1) * 4096 + wv * 1024 + s * 512);
            }
        }
        short8 afr[4], bfr[4];
        #pragma unroll
        for (int i = 0; i < 4; ++i)
            afr[i] = *(const short8*)(As + cur * 4096 +
                                      (wr + i * 16 + lrow) * 32 + quad * 8);
        #pragma unroll
        for (int j = 0; j < 4; ++j)
            bfr[j] = *(const short8*)(Bs + cur * 4096 +
                                      (wc + j * 16 + lrow) * 32 + quad * 8);
        #pragma unroll
        for (int i = 0; i < 4; ++i)
            #pragma unroll
            for (int j = 0; j < 4; ++j)
                acc[i][j] = __builtin_amdgcn_mfma_f32_16x16x32_bf16(
                    afr[i], bfr[j], acc[i][j], 0, 0, 0);
    }

    float mz[4][4];
    #pragma unroll
    for (int i = 0; i < 4; ++i)
        #pragma unroll
        for (int r = 0; r < 4; ++r) {
            int row = m0 + wr + i * 16 + quad * 4 + r;
            mz[i][r] = (qmask && qmask[row] == 255.0f) ? 0.f : 1.f;
        }

    #pragma unroll
    for (int i = 0; i < 4; ++i) {
        #pragma unroll
        for (int j = 0; j < 4; ++j) {
            int col = n0 + wc + j * 16 + lrow;
            if (col >= Nout) continue;
            float bsv = bias ? bias[col] : 0.f;
            #pragma unroll
            for (int r = 0; r < 4; ++r) {
                int row = m0 + wr + i * 16 + quad * 4 + r;
                float v = acc[i][j][r] + bsv;
                if (relu) v = fmaxf(v, 0.f);
                v *= mz[i][r];
                if (Cf) Cf[(size_t)row * Nout + col] = v;
                if (Cb) Cb[(size_t)row * Nout + col] = f2bf(v);
            }
        }
    }
}

template <int KT>
__global__ __launch_bounds__(256) void gemm_single_kernel(
        const ushort* __restrict__ A, const ushort* __restrict__ Wt,
        const float* __restrict__ bias,
        float* __restrict__ Cf, ushort* __restrict__ Cb,
        int Nout, int relu, const float* __restrict__ qmask) {
    __shared__ ushort As[2 * 128 * 32];
    __shared__ ushort Bs[2 * 128 * 32];
    gemm_core<KT>(A, Wt, bias, Cf, Cb, Nout, relu, qmask, As, Bs);
}

// dual dispatch: z=0 -> soaw projection, z=1 -> value projection (overlapped)
__global__ __launch_bounds__(256) void gemm_dual_kernel(
        const ushort* __restrict__ A0, const ushort* __restrict__ W0,
        const float* __restrict__ b0, float* __restrict__ Cf0,
        const ushort* __restrict__ A1, const ushort* __restrict__ W1,
        const float* __restrict__ b1, ushort* __restrict__ Cb1,
        const float* __restrict__ qmask) {
    __shared__ ushort As[2 * 128 * 32];
    __shared__ ushort Bs[2 * 128 * 32];
    if (blockIdx.z == 0)
        gemm_core<384>(A0, W0, b0, Cf0, nullptr, 384, 0, nullptr, As, Bs);
    else
        gemm_core<384>(A1, W1, b1, nullptr, Cb1, 384, 0, qmask, As, Bs);
}

// ---------------------------------------------------------------------------
// K3: full-row GEMM + LayerNorm fusion — R0 structure with T3/T4 sync:
//     64-row stripe, 512 threads (8 waves), grid 256, R0 staging layout,
//     but the K-loop uses COUNTED vmcnt + RAW s_barrier (no vmcnt(0) drain):
//       LDS: 4 buffers (A 4x4KB + B 4x24KB = 112KB), staged 3 chunks ahead.
//       iter c: s_waitcnt vmcnt(8|6)   [waves 0-3 issue 4 ops/chunk, 4-7
//                                       issue 3; completes chunk c exactly,
//                                       leaves c+1,c+2 in flight]
//               s_barrier + sched_barrier(0)   [cross-wave visibility; no
//                                               drain; fence vs hoisting]
//               stage(c+3) -> buf[(c+3)&3]     [WAR-safe: prior readers
//                                               (chunk c-1) done per barrier]
//               12 MFMA on buf[c&3]
//       tail waits 4|3 then 0. Coverage ~3 iterations >= L2 latency.
//     Epilogue identical to R0 (bitwise-same numerics).
//     MODE 0: residual bf16 (src), write q1_f (fp32) + q1_bf (bf16).
//     MODE 1: residual fp32 (q1), write transposed fp32 out[b,d,n] via
//             padded LDS tile (stride 193) overlaid on Bs, 2 col-halves.
// ---------------------------------------------------------------------------
template <int KT, int MODE>
__global__ __launch_bounds__(512) void gemm_fullrow_kernel(
        const ushort* __restrict__ A, const ushort* __restrict__ Wt,
        const float* __restrict__ bias, const void* __restrict__ resid,
        const float* __restrict__ g, const float* __restrict__ beta,
        float* __restrict__ outf, ushort* __restrict__ outb) {
    constexpr int NCH = KT / 32;
    __shared__ ushort As[4 * 2048];           // 16KB: 4 bufs x 64x32
    __shared__ ushort Bs[4 * 12288];          // 96KB: 4 bufs x 384x32
    __shared__ float eps1[8][64], eps2[8][64];
    __shared__ float mu_l[64], rs_l[64];
    const int tid  = threadIdx.x;
    const int lane = tid & 63;
    const int wv   = tid >> 6;                // 0..7
    const int quad = lane >> 4;
    const int lrow = lane & 15;
    const int m0   = blockIdx.x * 64;
    const int srow = lane >> 2;               // 0..15
    const int scol = (lane & 3) * 8;

    floatx4 acc[4][3];
    #pragma unroll
    for (int i = 0; i < 4; ++i)
        #pragma unroll
        for (int j = 0; j < 3; ++j)
            acc[i][j] = (floatx4)(0.f);

#define STAGE_CHUNK(c, buf)                                                   \
    {   const int k0_ = (c) * 32;                                             \
        if (wv < 4)                                                           \
            gload_lds16(A + (size_t)(m0 + wv * 16 + srow) * KT + k0_ + scol,  \
                        As + (buf) * 2048 + wv * 512);                        \
        _Pragma("unroll")                                                     \
        for (int s_ = 0; s_ < 3; ++s_)                                        \
            gload_lds16(Wt + (size_t)(wv * 48 + s_ * 16 + srow) * KT + k0_ + scol, \
                        Bs + (buf) * 12288 + wv * 1536 + s_ * 512);           \
    }

    // prologue: stage chunks 0,1,2 -> bufs 0,1,2 (12 or 9 ops outstanding)
    STAGE_CHUNK(0, 0)
    STAGE_CHUNK(1, 1)
    STAGE_CHUNK(2, 2)

    #pragma unroll
    for (int c = 0; c < NCH; ++c) {
        const int rem = (NCH - 1 - c) >= 2 ? 2 : (NCH - 1 - c);
        if (wv < 4) {
            if (rem == 2)      asm volatile("s_waitcnt vmcnt(8)" ::: "memory");
            else if (rem == 1) asm volatile("s_waitcnt vmcnt(4)" ::: "memory");
            else               asm volatile("s_waitcnt vmcnt(0)" ::: "memory");
        } else {
            if (rem == 2)      asm volatile("s_waitcnt vmcnt(6)" ::: "memory");
            else if (rem == 1) asm volatile("s_waitcnt vmcnt(3)" ::: "memory");
            else               asm volatile("s_waitcnt vmcnt(0)" ::: "memory");
        }
        __builtin_amdgcn_s_barrier();
        __builtin_amdgcn_sched_barrier(0);
        if (c + 3 < NCH) { STAGE_CHUNK(c + 3, (c + 3) & 3) }
        const int buf = c & 3;
        short8 afr[4], bfr[3];
        #pragma unroll
        for (int i = 0; i < 4; ++i)
            afr[i] = *(const short8*)(As + buf * 2048 +
                                      (i * 16 + lrow) * 32 + quad * 8);
        #pragma unroll
        for (int j = 0; j < 3; ++j)
            bfr[j] = *(const short8*)(Bs + buf * 12288 +
                                      (wv * 48 + j * 16 + lrow) * 32 + quad * 8);
        #pragma unroll
        for (int i = 0; i < 4; ++i)
            #pragma unroll
            for (int j = 0; j < 3; ++j)
                acc[i][j] = __builtin_amdgcn_mfma_f32_16x16x32_bf16(
                    afr[i], bfr[j], acc[i][j], 0, 0, 0);
    }
#undef STAGE_CHUNK

    // --- epilogue: residual add + row-sum (R0-verified, unchanged) ---
    float s1[16], s2[16];
    #pragma unroll
    for (int k = 0; k < 16; ++k) { s1[k] = 0.f; s2[k] = 0.f; }
    #pragma unroll
    for (int i = 0; i < 4; ++i) {
        #pragma unroll
        for (int r = 0; r < 4; ++r) {
            int rl = i * 16 + quad * 4 + r;
            #pragma unroll
            for (int j = 0; j < 3; ++j) {
                int col = wv * 48 + j * 16 + lrow;
                float t = acc[i][j][r];
                if (bias) t += bias[col];
                if (MODE == 0)
                    t += bf2f(((const ushort*)resid)[(size_t)(m0 + rl) * Dc + col]);
                else
                    t += ((const float*)resid)[(size_t)(m0 + rl) * Dc + col];
                acc[i][j][r] = t;
                s1[i * 4 + r] += t;
                s2[i * 4 + r] += t * t;
            }
        }
    }
    // reduce over the 16 lrow lanes (bits 0..3 of lane id)
    #pragma unroll
    for (int mm = 1; mm < 16; mm <<= 1) {
        #pragma unroll
        for (int k = 0; k < 16; ++k) {
            s1[k] += __shfl_xor(s1[k], mm);
            s2[k] += __shfl_xor(s2[k], mm);
        }
    }
    if (lrow == 0) {
        #pragma unroll
        for (int i = 0; i < 4; ++i)
            #pragma unroll
            for (int r = 0; r < 4; ++r) {
                int rl = i * 16 + quad * 4 + r;
                eps1[wv][rl] = s1[i * 4 + r];
                eps2[wv][rl] = s2[i * 4 + r];
            }
    }
    __syncthreads();
    if (tid < 64) {
        float a1 = 0.f, a2 = 0.f;
        #pragma unroll
        for (int w = 0; w < 8; ++w) { a1 += eps1[w][tid]; a2 += eps2[w][tid]; }
        float mu  = a1 * (1.0f / Dc);
        float var = a2 * (1.0f / Dc) - mu * mu;
        mu_l[tid] = mu;
        rs_l[tid] = rsqrtf(var + 1e-5f);
    }
    __syncthreads();

    // normalize in place
    #pragma unroll
    for (int i = 0; i < 4; ++i) {
        #pragma unroll
        for (int r = 0; r < 4; ++r) {
            int rl = i * 16 + quad * 4 + r;
            float mu = mu_l[rl], rs = rs_l[rl];
            #pragma unroll
            for (int j = 0; j < 3; ++j) {
                int col = wv * 48 + j * 16 + lrow;
                acc[i][j][r] = (acc[i][j][r] - mu) * rs * g[col] + beta[col];
            }
        }
    }

    if (MODE == 0) {
        #pragma unroll
        for (int i = 0; i < 4; ++i)
            #pragma unroll
            for (int j = 0; j < 3; ++j) {
                int col = wv * 48 + j * 16 + lrow;
                #pragma unroll
                for (int r = 0; r < 4; ++r) {
                    int rl = i * 16 + quad * 4 + r;
                    float v = acc[i][j][r];
                    outf[(size_t)(m0 + rl) * Dc + col] = v;
                    outb[(size_t)(m0 + rl) * Dc + col] = f2bf(v);
                }
            }
    } else {
        // transposed write via LDS tile (64 rows x 192 cols, stride 193)
        float* tile = (float*)Bs;
        const int b   = m0 >> 12;
        const int n0r = m0 & 4095;
        #pragma unroll
        for (int gp = 0; gp < 2; ++gp) {
            __syncthreads();                  // tile free / prev pass done
            if ((wv >> 2) == gp) {
                int cbase = (wv & 3) * 48;
                #pragma unroll
                for (int i = 0; i < 4; ++i)
                    #pragma unroll
                    for (int j = 0; j < 3; ++j) {
                        int c = cbase + j * 16 + lrow;
                        #pragma unroll
                        for (int r = 0; r < 4; ++r) {
                            int rl = i * 16 + quad * 4 + r;
                            tile[rl * 193 + c] = acc[i][j][r];
                        }
                    }
            }
            __syncthreads();
            const int row = tid & 63;
            const int cp  = tid >> 6;         // 0..7
            #pragma unroll
            for (int it = 0; it < 24; ++it) {
                int c = it * 8 + cp;
                outf[((size_t)(b * Dc + gp * 192 + c)) * Nc + n0r + row] =
                    tile[row * 193 + c];
            }
        }
    }
}

// ---------------------------------------------------------------------------
// K4: deformable attention gather (softmax fused).
//     Slice-major mapping: one block = one (b,m) value slice x one image row h
//     (64 consecutive n). Sampling taps cluster in ~5 rows of ONE 256KB slice
//     (~20KB footprint -> L1-resident). bid = chunk*48 + slice with 48%8==0
//     -> all 64 blocks of a slice share bid%8 (same XCD) -> slice L2-resident.
// ---------------------------------------------------------------------------
__global__ __launch_bounds__(256) void deform_attn_kernel(
        const ushort* __restrict__ value_bf, const float* __restrict__ soaw,
        ushort* __restrict__ out) {
    int bid   = blockIdx.x;                            // 0..3071 = 64 chunks * 48 slices
    int slice = bid % 48;                              // b*M + m  (same-XCD per slice)
    int h     = bid / 48;                              // image row
    int m  = slice % Mc;
    int b  = slice / Mc;
    int w  = threadIdx.x >> 2;                         // 0..63 (column)
    int l4 = threadIdx.x & 3;                          // channel octet
    int n  = (h << 6) | w;
    int bn = b * Nc + n;
    const float* sop = soaw + (size_t)bn * 384 + m * 18;
    const float* lgt = soaw + (size_t)bn * 384 + 216 + m * Pc;
    float awv[Pc];
    float mx = lgt[0];
    #pragma unroll
    for (int i = 1; i < Pc; ++i) mx = fmaxf(mx, lgt[i]);
    float ssum = 0.f;
    #pragma unroll
    for (int i = 0; i < Pc; ++i) { awv[i] = __expf(lgt[i] - mx); ssum += awv[i]; }
    float sinv = 1.f / ssum;
    const ushort* vb = value_bf + ((size_t)b * Nc) * Dc + m * DHc + l4 * 8;
    float acc[8] = {0.f, 0.f, 0.f, 0.f, 0.f, 0.f, 0.f, 0.f};
    #pragma unroll
    for (int p = 0; p < Pc; ++p) {
        float2 so2 = *(const float2*)(sop + p * 2);
        float px = (float)w + so2.x;
        float py = (float)h + so2.y;
        float x0f = floorf(px), y0f = floorf(py);
        float lx = px - x0f, ly = py - y0f;
        int x0 = (int)x0f, y0 = (int)y0f;
        int x1 = x0 + 1,  y1 = y0 + 1;
        float a = awv[p] * sinv;
        float w00 = (1.f - lx) * (1.f - ly) * a;
        float w01 = lx * (1.f - ly) * a;
        float w10 = (1.f - lx) * ly * a;
        float w11 = lx * ly * a;
        bool bx0 = (unsigned)x0 < 64u, bx1 = (unsigned)x1 < 64u;
        bool by0 = (unsigned)y0 < 64u, by1 = (unsigned)y1 < 64u;
        w00 = (bx0 && by0) ? w00 : 0.f;
        w01 = (bx1 && by0) ? w01 : 0.f;
        w10 = (bx0 && by1) ? w10 : 0.f;
        w11 = (bx1 && by1) ? w11 : 0.f;
        int cx0 = min(max(x0, 0), 63), cx1 = min(max(x1, 0), 63);
        int cy0 = min(max(y0, 0), 63), cy1 = min(max(y1, 0), 63);
        uint4 q00 = *(const uint4*)(vb + (size_t)(cy0 * 64 + cx0) * Dc);
        uint4 q01 = *(const uint4*)(vb + (size_t)(cy0 * 64 + cx1) * Dc);
        uint4 q10 = *(const uint4*)(vb + (size_t)(cy1 * 64 + cx0) * Dc);
        uint4 q11 = *(const uint4*)(vb + (size_t)(cy1 * 64 + cx1) * Dc);
        union { unsigned u; float f; } t;
        #define ACC2(word, wg, k)                                   \
            t.u = (word) << 16;         acc[k]     += (wg) * t.f;   \
            t.u = (word) & 0xffff0000u; acc[k + 1] += (wg) * t.f;
        #define ACC8(q, wg) \
            ACC2((q).x, wg, 0) ACC2((q).y, wg, 2) ACC2((q).z, wg, 4) ACC2((q).w, wg, 6)
        ACC8(q00, w00) ACC8(q01, w01) ACC8(q10, w10) ACC8(q11, w11)
        #undef ACC8
        #undef ACC2
    }
    short8 o;
    #pragma unroll
    for (int k = 0; k < 8; ++k) o[k] = (short)f2bf(acc[k]);
    *(short8*)(out + (size_t)bn * Dc + m * DHc + l4 * 8) = o;
}

// ---------------------------------------------------------------------------
extern "C" void kernel_launch(void* const* d_in, const int* in_sizes, int n_in,
                              void* d_out, int out_size, void* d_ws, size_t ws_size,
                              hipStream_t stream) {
    (void)in_sizes; (void)n_in; (void)out_size; (void)ws_size;
    const float* x      = (const float*)d_in[0];
    const float* qmask  = (const float*)d_in[1];
    const float* so_w   = (const float*)d_in[2];
    const float* so_b   = (const float*)d_in[3];
    const float* aw_w   = (const float*)d_in[4];
    const float* aw_b   = (const float*)d_in[5];
    const float* vp_w   = (const float*)d_in[6];
    const float* vp_b   = (const float*)d_in[7];
    const float* op_w   = (const float*)d_in[8];
    const float* op_b   = (const float*)d_in[9];
    const float* ln1_g  = (const float*)d_in[10];
    const float* ln1_b  = (const float*)d_in[11];
    const float* w1     = (const float*)d_in[12];
    const float* w2     = (const float*)d_in[13];
    const float* ln2_g  = (const float*)d_in[14];
    const float* ln2_b  = (const float*)d_in[15];
    const float* lvl    = (const float*)d_in[16];
    float* out = (float*)d_out;

    // Workspace (~104 MB):
    float*  ws       = (float*)d_ws;
    float*  q1_f     = ws;                          // 6291456 f (LN1 out / LN2 residual)
    ushort* src_bf   = (ushort*)(q1_f + 6291456);   // 6291456 us
    ushort* qpos_bf  = src_bf + 6291456;            // 6291456 us (qpos->attn->q1_bf)
    ushort* value_bf = qpos_bf + 6291456;           // 6291456 us
    ushort* hbuf_bf  = value_bf + 6291456;          // 18874368 us (FFN hidden)
    float*  soaw_f   = (float*)hbuf_bf;             // 6291456 f overlay (dead pre-FFN1)
    ushort* wbuf     = hbuf_bf + 18874368;          // 1304064 us
    float*  soaw_bias= (float*)(wbuf + 1304064);    // 384 f (padded)
    float*  cum_y    = soaw_bias + 384;             // 16384 f
    float*  cum_x    = cum_y + 16384;               // 16384 f

    const ushort* soaw_wb = wbuf;                   // [324,384] (so_w ++ aw_w)
    const ushort* vp_wb = soaw_wb + SOW_N + AWW_N;
    const ushort* op_wb = vp_wb + VPW_N;
    const ushort* w1_b  = op_wb + OPW_N;
    const ushort* w2_b  = w1_b + W1_N;

    // 0) fused init (weights + bias)
    init_kernel<<<(WTOT + 384 + 255) / 256, 256, 0, stream>>>(
        so_w, aw_w, vp_w, op_w, w1, w2, so_b, aw_b, wbuf, soaw_bias);
    // 0b) mask cumsums via LDS scan
    cumsum_kernel<<<Bc, 256, 0, stream>>>(qmask, cum_y, cum_x);
    // 1) transpose + pos encode
    transpose_pos_kernel<<<dim3(Nc / 32, Dc / 32, Bc), dim3(32, 32), 0, stream>>>(
        x, cum_y, cum_x, lvl, src_bf, qpos_bf);
    // 2) DUAL: z=0 soaw projection (fp32 out), z=1 value projection (bf16+mask)
    gemm_dual_kernel<<<dim3(BNc / 128, 3, 2), 256, 0, stream>>>(
        qpos_bf, soaw_wb, soaw_bias, soaw_f,
        src_bf, vp_wb, vp_b, value_bf, qmask);
    // 3) deformable gather (softmax fused, slice-major) -> attn into qpos_bf
    deform_attn_kernel<<<3072, 256, 0, stream>>>(
        value_bf, soaw_f, qpos_bf);
    // 4) fused op-proj + residual(src_bf) + LN1 -> q1_f + q1_bf (in qpos_bf)
    gemm_fullrow_kernel<384, 0><<<BNc / 64, 512, 0, stream>>>(
        qpos_bf, op_wb, op_b, src_bf, ln1_g, ln1_b, q1_f, qpos_bf);
    // 5) FFN1 (relu, bf16 hidden)
    gemm_single_kernel<384><<<dim3(BNc / 128, 9), 256, 0, stream>>>(
        qpos_bf, w1_b, nullptr, nullptr, hbuf_bf, DFFc, 1, nullptr);
    // 6) fused FFN2 + residual(q1_f) + LN2 + transpose -> out[B,D,N]
    gemm_fullrow_kernel<1152, 1><<<BNc / 64, 512, 0, stream>>>(
        hbuf_bf, w2_b, nullptr, q1_f, ln2_g, ln2_b, out, nullptr);
}

// Round 6
// 259.426 us; speedup vs baseline: 1.2313x; 1.0398x over previous
//
#include <hip/hip_runtime.h>
#include <math.h>

// Problem constants
#define Bc   4
#define Hc   64
#define Wc   64
#define Dc   384
#define Nc   4096      // H*W
#define Mc   12
#define Pc   9
#define DHc  32
#define DFFc 1152
#define BNc  (Bc*Nc)   // 16384

typedef __attribute__((ext_vector_type(8))) short short8;
typedef __attribute__((ext_vector_type(4))) float floatx4;

__device__ __forceinline__ ushort f2bf(float f) {
    union { float f; unsigned u; } v; v.f = f;
    unsigned r = v.u + 0x7fffu + ((v.u >> 16) & 1u);   // RNE
    return (ushort)(r >> 16);
}
__device__ __forceinline__ float bf2f(ushort u) {
    union { unsigned u; float f; } v; v.u = (unsigned)u << 16; return v.f;
}

__device__ __forceinline__ void gload_lds16(const void* g, void* l) {
    __builtin_amdgcn_global_load_lds(
        (const __attribute__((address_space(1))) void*)(uintptr_t)g,
        (__attribute__((address_space(3))) void*)(uintptr_t)l,
        16, 0, 0);
}

// ---------------------------------------------------------------------------
// K0: fused init — weight fp32->bf16 convert, bias concat.
// ---------------------------------------------------------------------------
#define SOW_N  82944     // 216*384
#define AWW_N  41472     // 108*384
#define VPW_N  147456    // 384*384
#define OPW_N  147456
#define W1_N   442368    // 1152*384
#define W2_N   442368    // 384*1152
#define WTOT   1304064

__global__ void init_kernel(const float* __restrict__ so_w,
                            const float* __restrict__ aw_w,
                            const float* __restrict__ vp_w,
                            const float* __restrict__ op_w,
                            const float* __restrict__ w1,
                            const float* __restrict__ w2,
                            const float* __restrict__ so_b,
                            const float* __restrict__ aw_b,
                            ushort* __restrict__ out,
                            float* __restrict__ bias_out) {
    int i = blockIdx.x * 256 + threadIdx.x;
    if (i < WTOT) {
        float v;
        int j = i;
        if (j < SOW_N) v = so_w[j];
        else if ((j -= SOW_N) < AWW_N) v = aw_w[j];
        else if ((j -= AWW_N) < VPW_N) v = vp_w[j];
        else if ((j -= VPW_N) < OPW_N) v = op_w[j];
        else if ((j -= OPW_N) < W1_N)  v = w1[j];
        else { j -= W1_N; v = w2[j]; }
        out[i] = f2bf(v);
        return;
    }
    int j = i - WTOT;
    if (j < 384) {   // pad bias to 384 with zeros (col-tile over-read safety)
        bias_out[j] = (j < 216) ? so_b[j] : (j < 324 ? aw_b[j - 216] : 0.f);
    }
}

// ---------------------------------------------------------------------------
// K0b: mask cumsums via LDS (coalesced loads/stores, scans over LDS).
// ---------------------------------------------------------------------------
__global__ __launch_bounds__(256) void cumsum_kernel(
        const float* __restrict__ qmask,
        float* __restrict__ cum_y, float* __restrict__ cum_x) {
    __shared__ float nm[64 * 65];     // stride 65: conflict-free rows AND cols
    __shared__ float ot[64 * 65];
    int b = blockIdx.x;
    int t = threadIdx.x;
    const float* qm = qmask + b * 4096;
    #pragma unroll
    for (int k = 0; k < 16; ++k) {
        int idx = t + k * 256;
        nm[(idx >> 6) * 65 + (idx & 63)] = (qm[idx] == 255.0f) ? 0.f : 1.f;
    }
    __syncthreads();
    if (t < 64) {                     // column scan over h (cum_y), t = w
        float run = 0.f;
        for (int h = 0; h < 64; ++h) { run += nm[h * 65 + t]; ot[h * 65 + t] = run; }
    }
    __syncthreads();
    #pragma unroll
    for (int k = 0; k < 16; ++k) {
        int idx = t + k * 256;
        cum_y[b * 4096 + idx] = ot[(idx >> 6) * 65 + (idx & 63)];
    }
    __syncthreads();
    if (t < 64) {                     // row scan over w (cum_x), t = h
        float run = 0.f;
        for (int w = 0; w < 64; ++w) { run += nm[t * 65 + w]; ot[t * 65 + w] = run; }
    }
    __syncthreads();
    #pragma unroll
    for (int k = 0; k < 16; ++k) {
        int idx = t + k * 256;
        cum_x[b * 4096 + idx] = ot[(idx >> 6) * 65 + (idx & 63)];
    }
}

// ---------------------------------------------------------------------------
// K1: transpose x[B,D,N] -> src_bf[B,N,D] (bf16);
//     qpos_bf = bf16(src + sine_pos + level_embed). Fast-math trig.
// ---------------------------------------------------------------------------
__global__ void transpose_pos_kernel(const float* __restrict__ x,
                                     const float* __restrict__ cum_y,
                                     const float* __restrict__ cum_x,
                                     const float* __restrict__ level_embed,
                                     ushort* __restrict__ src_bf,
                                     ushort* __restrict__ qpos_bf) {
    __shared__ float tile[32][33];
    int b  = blockIdx.z;
    int n0 = blockIdx.x * 32, d0 = blockIdx.y * 32;
    int tx = threadIdx.x, ty = threadIdx.y;
    tile[ty][tx] = x[((size_t)b * Dc + (d0 + ty)) * Nc + (n0 + tx)];
    __syncthreads();
    int n = n0 + ty, d = d0 + tx;
    float v = tile[tx][ty];
    size_t oi = ((size_t)b * Nc + n) * Dc + d;
    src_bf[oi] = f2bf(v);
    int h = n >> 6, w = n & 63;
    const float TWO_PI = 6.28318530717958647692f;
    float vy = cum_y[(b * Hc + h) * Wc + w] /
               (cum_y[(b * Hc + (Hc - 1)) * Wc + w] + 1e-6f) * TWO_PI;
    float vx = cum_x[(b * Hc + h) * Wc + w] /
               (cum_x[(b * Hc + h) * Wc + (Wc - 1)] + 1e-6f) * TWO_PI;
    int   i  = (d < 192) ? d : d - 192;
    float vv = (d < 192) ? vy : vx;
    float e   = (float)(i >> 1) * (2.0f / 192.0f);
    float idt = exp2f(e * -13.28771237954945f);
    float ang = vv * idt;
    float pe  = (i & 1) ? __cosf(ang) : __sinf(ang);
    qpos_bf[oi] = f2bf(v + pe + level_embed[d]);
}

// ---------------------------------------------------------------------------
// K2: bf16 MFMA GEMM core: 128x128 tile, global_load_lds, double-buffered
//     LDS, one barrier/K-chunk (used by the dual projection kernel).
// ---------------------------------------------------------------------------
template <int KT>
__device__ __forceinline__ void gemm_core(
        const ushort* __restrict__ A, const ushort* __restrict__ Wt,
        const float* __restrict__ bias,
        float* __restrict__ Cf, ushort* __restrict__ Cb,
        int Nout, int relu, const float* __restrict__ qmask,
        ushort* As, ushort* Bs) {           // As/Bs: 2 x 128*32 each
    constexpr int NCH = KT / 32;
    const int tid  = threadIdx.x;
    const int m0   = blockIdx.x * 128;
    const int n0   = blockIdx.y * 128;
    const int lane = tid & 63;
    const int wv   = tid >> 6;
    const int wr   = (wv >> 1) * 64;
    const int wc   = (wv & 1) * 64;
    const int quad = lane >> 4;
    const int lrow = lane & 15;
    const int srow = wv * 32 + (lane >> 2);
    const int scol = (lane & 3) * 8;

    floatx4 acc[4][4];
    #pragma unroll
    for (int i = 0; i < 4; ++i)
        #pragma unroll
        for (int j = 0; j < 4; ++j)
            acc[i][j] = (floatx4)(0.f);

    #pragma unroll
    for (int s = 0; s < 2; ++s) {
        gload_lds16(A  + (size_t)(m0 + srow + s * 16) * KT + scol,
                    As + wv * 1024 + s * 512);
        gload_lds16(Wt + (size_t)(n0 + srow + s * 16) * KT + scol,
                    Bs + wv * 1024 + s * 512);
    }

    for (int c = 0; c < NCH; ++c) {
        const int cur = c & 1;
        __syncthreads();
        if (c + 1 < NCH) {
            const int k0 = (c + 1) * 32;
            #pragma unroll
            for (int s = 0; s < 2; ++s) {
                gload_lds16(A  + (size_t)(m0 + srow + s * 16) * KT + k0 + scol,
                            As + (cur ^ 1) * 4096 + wv * 1024 + s * 512);
                gload_lds16(Wt + (size_t)(n0 + srow + s * 16) * KT + k0 + scol,
                            Bs + (cur ^ 1) * 4096 + wv * 1024 + s * 512);
            }
        }
        short8 afr[4], bfr[4];
        #pragma unroll
        for (int i = 0; i < 4; ++i)
            afr[i] = *(const short8*)(As + cur * 4096 +
                                      (wr + i * 16 + lrow) * 32 + quad * 8);
        #pragma unroll
        for (int j = 0; j < 4; ++j)
            bfr[j] = *(const short8*)(Bs + cur * 4096 +
                                      (wc + j * 16 + lrow) * 32 + quad * 8);
        #pragma unroll
        for (int i = 0; i < 4; ++i)
            #pragma unroll
            for (int j = 0; j < 4; ++j)
                acc[i][j] = __builtin_amdgcn_mfma_f32_16x16x32_bf16(
                    afr[i], bfr[j], acc[i][j], 0, 0, 0);
    }

    float mz[4][4];
    #pragma unroll
    for (int i = 0; i < 4; ++i)
        #pragma unroll
        for (int r = 0; r < 4; ++r) {
            int row = m0 + wr + i * 16 + quad * 4 + r;
            mz[i][r] = (qmask && qmask[row] == 255.0f) ? 0.f : 1.f;
        }

    #pragma unroll
    for (int i = 0; i < 4; ++i) {
        #pragma unroll
        for (int j = 0; j < 4; ++j) {
            int col = n0 + wc + j * 16 + lrow;
            if (col >= Nout) continue;
            float bsv = bias ? bias[col] : 0.f;
            #pragma unroll
            for (int r = 0; r < 4; ++r) {
                int row = m0 + wr + i * 16 + quad * 4 + r;
                float v = acc[i][j][r] + bsv;
                if (relu) v = fmaxf(v, 0.f);
                v *= mz[i][r];
                if (Cf) Cf[(size_t)row * Nout + col] = v;
                if (Cb) Cb[(size_t)row * Nout + col] = f2bf(v);
            }
        }
    }
}

// dual dispatch: z=0 -> soaw projection, z=1 -> value projection (overlapped)
__global__ __launch_bounds__(256) void gemm_dual_kernel(
        const ushort* __restrict__ A0, const ushort* __restrict__ W0,
        const float* __restrict__ b0, float* __restrict__ Cf0,
        const ushort* __restrict__ A1, const ushort* __restrict__ W1,
        const float* __restrict__ b1, ushort* __restrict__ Cb1,
        const float* __restrict__ qmask) {
    __shared__ ushort As[2 * 128 * 32];
    __shared__ ushort Bs[2 * 128 * 32];
    if (blockIdx.z == 0)
        gemm_core<384>(A0, W0, b0, Cf0, nullptr, 384, 0, nullptr, As, Bs);
    else
        gemm_core<384>(A1, W1, b1, nullptr, Cb1, 384, 0, qmask, As, Bs);
}

// ---------------------------------------------------------------------------
// K3: full-row GEMM + LayerNorm fusion (LN1) — R5-verified counted-vmcnt:
//     64-row stripe, 512 threads, grid 256, 4-buffer LDS, staged 3 ahead,
//     raw s_barrier (no drain) per chunk. Residual bf16, writes q1_f + q1_bf.
// ---------------------------------------------------------------------------
template <int KT>
__global__ __launch_bounds__(512) void gemm_fullrow_kernel(
        const ushort* __restrict__ A, const ushort* __restrict__ Wt,
        const float* __restrict__ bias, const void* __restrict__ resid,
        const float* __restrict__ g, const float* __restrict__ beta,
        float* __restrict__ outf, ushort* __restrict__ outb) {
    constexpr int NCH = KT / 32;
    __shared__ ushort As[4 * 2048];           // 16KB: 4 bufs x 64x32
    __shared__ ushort Bs[4 * 12288];          // 96KB: 4 bufs x 384x32
    __shared__ float eps1[8][64], eps2[8][64];
    __shared__ float mu_l[64], rs_l[64];
    const int tid  = threadIdx.x;
    const int lane = tid & 63;
    const int wv   = tid >> 6;                // 0..7
    const int quad = lane >> 4;
    const int lrow = lane & 15;
    const int m0   = blockIdx.x * 64;
    const int srow = lane >> 2;               // 0..15
    const int scol = (lane & 3) * 8;

    floatx4 acc[4][3];
    #pragma unroll
    for (int i = 0; i < 4; ++i)
        #pragma unroll
        for (int j = 0; j < 3; ++j)
            acc[i][j] = (floatx4)(0.f);

#define STAGE_CHUNK(c, buf)                                                   \
    {   const int k0_ = (c) * 32;                                             \
        if (wv < 4)                                                           \
            gload_lds16(A + (size_t)(m0 + wv * 16 + srow) * KT + k0_ + scol,  \
                        As + (buf) * 2048 + wv * 512);                        \
        _Pragma("unroll")                                                     \
        for (int s_ = 0; s_ < 3; ++s_)                                        \
            gload_lds16(Wt + (size_t)(wv * 48 + s_ * 16 + srow) * KT + k0_ + scol, \
                        Bs + (buf) * 12288 + wv * 1536 + s_ * 512);           \
    }

    // prologue: stage chunks 0,1,2 -> bufs 0,1,2
    STAGE_CHUNK(0, 0)
    STAGE_CHUNK(1, 1)
    STAGE_CHUNK(2, 2)

    #pragma unroll
    for (int c = 0; c < NCH; ++c) {
        const int rem = (NCH - 1 - c) >= 2 ? 2 : (NCH - 1 - c);
        if (wv < 4) {
            if (rem == 2)      asm volatile("s_waitcnt vmcnt(8)" ::: "memory");
            else if (rem == 1) asm volatile("s_waitcnt vmcnt(4)" ::: "memory");
            else               asm volatile("s_waitcnt vmcnt(0)" ::: "memory");
        } else {
            if (rem == 2)      asm volatile("s_waitcnt vmcnt(6)" ::: "memory");
            else if (rem == 1) asm volatile("s_waitcnt vmcnt(3)" ::: "memory");
            else               asm volatile("s_waitcnt vmcnt(0)" ::: "memory");
        }
        __builtin_amdgcn_s_barrier();
        __builtin_amdgcn_sched_barrier(0);
        if (c + 3 < NCH) { STAGE_CHUNK(c + 3, (c + 3) & 3) }
        const int buf = c & 3;
        short8 afr[4], bfr[3];
        #pragma unroll
        for (int i = 0; i < 4; ++i)
            afr[i] = *(const short8*)(As + buf * 2048 +
                                      (i * 16 + lrow) * 32 + quad * 8);
        #pragma unroll
        for (int j = 0; j < 3; ++j)
            bfr[j] = *(const short8*)(Bs + buf * 12288 +
                                      (wv * 48 + j * 16 + lrow) * 32 + quad * 8);
        #pragma unroll
        for (int i = 0; i < 4; ++i)
            #pragma unroll
            for (int j = 0; j < 3; ++j)
                acc[i][j] = __builtin_amdgcn_mfma_f32_16x16x32_bf16(
                    afr[i], bfr[j], acc[i][j], 0, 0, 0);
    }
#undef STAGE_CHUNK

    // --- epilogue: residual add + row-sum -> LN ---
    float s1[16], s2[16];
    #pragma unroll
    for (int k = 0; k < 16; ++k) { s1[k] = 0.f; s2[k] = 0.f; }
    #pragma unroll
    for (int i = 0; i < 4; ++i) {
        #pragma unroll
        for (int r = 0; r < 4; ++r) {
            int rl = i * 16 + quad * 4 + r;
            #pragma unroll
            for (int j = 0; j < 3; ++j) {
                int col = wv * 48 + j * 16 + lrow;
                float t = acc[i][j][r];
                if (bias) t += bias[col];
                t += bf2f(((const ushort*)resid)[(size_t)(m0 + rl) * Dc + col]);
                acc[i][j][r] = t;
                s1[i * 4 + r] += t;
                s2[i * 4 + r] += t * t;
            }
        }
    }
    #pragma unroll
    for (int mm = 1; mm < 16; mm <<= 1) {
        #pragma unroll
        for (int k = 0; k < 16; ++k) {
            s1[k] += __shfl_xor(s1[k], mm);
            s2[k] += __shfl_xor(s2[k], mm);
        }
    }
    if (lrow == 0) {
        #pragma unroll
        for (int i = 0; i < 4; ++i)
            #pragma unroll
            for (int r = 0; r < 4; ++r) {
                int rl = i * 16 + quad * 4 + r;
                eps1[wv][rl] = s1[i * 4 + r];
                eps2[wv][rl] = s2[i * 4 + r];
            }
    }
    __syncthreads();
    if (tid < 64) {
        float a1 = 0.f, a2 = 0.f;
        #pragma unroll
        for (int w = 0; w < 8; ++w) { a1 += eps1[w][tid]; a2 += eps2[w][tid]; }
        float mu  = a1 * (1.0f / Dc);
        float var = a2 * (1.0f / Dc) - mu * mu;
        mu_l[tid] = mu;
        rs_l[tid] = rsqrtf(var + 1e-5f);
    }
    __syncthreads();
    #pragma unroll
    for (int i = 0; i < 4; ++i) {
        #pragma unroll
        for (int r = 0; r < 4; ++r) {
            int rl = i * 16 + quad * 4 + r;
            float mu = mu_l[rl], rs = rs_l[rl];
            #pragma unroll
            for (int j = 0; j < 3; ++j) {
                int col = wv * 48 + j * 16 + lrow;
                float v = (acc[i][j][r] - mu) * rs * g[col] + beta[col];
                outf[(size_t)(m0 + rl) * Dc + col] = v;
                outb[(size_t)(m0 + rl) * Dc + col] = f2bf(v);
            }
        }
    }
}

// ---------------------------------------------------------------------------
// K5: FUSED FFN (FFN1+relu+FFN2) + residual + LN2 + transposed write.
//     Grid 256 (64-row stripe), 512 threads (8 waves), 1 block/CU.
//     Per hidden-chunk hc (9 x 128): GEMM1 (12 kc, W1 wave-private ring-3,
//     depth-2 counted vmcnt) -> relu+f2bf -> hblk 64x128 bf16 in LDS ->
//     barrier -> GEMM2 (4 kc2, W2 wave-private ring-2, counted vmcnt,
//     accumulating acc2 over all hc in ascending hidden order == old FFN2
//     chunk order) -> barrier. A-stripe (48KB) staged once. MFMA sequence
//     bitwise-identical to the old FFN1->hbuf->FFN2 path.
//     Wave-private FIFO waits (16B ops): G1 steady vmcnt(2); kc=10: issue
//     W2(0) -> vmcnt(4); kc=11: issue W2(1) -> vmcnt(6). G2: vmcnt(3)/
//     (4)/(5)/(1) with W2(next)+W1'(next-hc) staged after each slot's reads.
//     LDS: A 48K + hblk 16K + W1 24K + W2 48K = 136K (+LN scratch).
// ---------------------------------------------------------------------------
__global__ __launch_bounds__(512) void ffn_fused_kernel(
        const ushort* __restrict__ A,      // q1_bf [BN][384]
        const ushort* __restrict__ W1b,    // [1152][384]
        const ushort* __restrict__ W2b,    // [384][1152]
        const float* __restrict__ resid,   // q1_f
        const float* __restrict__ g, const float* __restrict__ beta,
        float* __restrict__ outf) {
    __shared__ ushort smem[69632];         // 136KB carved below
    ushort* Ast = smem;                    // 12 chunks x [64][32] = 24576
    ushort* Hs  = smem + 24576;            // 4 chunks x [64][32]  = 8192
    ushort* W1s = smem + 32768;            // 8 waves x 3 bufs x 512
    ushort* W2s = smem + 45056;            // 8 waves x 2 bufs x 1536
    __shared__ float eps1[8][64], eps2[8][64];
    __shared__ float mu_l[64], rs_l[64];

    const int tid  = threadIdx.x;
    const int lane = tid & 63;
    const int wv   = tid >> 6;
    const int quad = lane >> 4;
    const int lrow = lane & 15;
    const int m0   = blockIdx.x * 64;
    const int srow = lane >> 2;
    const int scol = (lane & 3) * 8;

    ushort* W1w = W1s + wv * 1536;
    ushort* W2w = W2s + wv * 3072;

    floatx4 acc2[4][3];
    #pragma unroll
    for (int i = 0; i < 4; ++i)
        #pragma unroll
        for (int j = 0; j < 3; ++j)
            acc2[i][j] = (floatx4)(0.f);

#define STAGE_W1(hcv, kcv, buf)                                               \
    gload_lds16(W1b + (size_t)((hcv) * 128 + wv * 16 + srow) * 384 + (kcv) * 32 + scol, \
                W1w + (buf) * 512 + lane * 8);

#define STAGE_W2(hcv, kc2v, buf)                                              \
    _Pragma("unroll")                                                         \
    for (int s_ = 0; s_ < 3; ++s_)                                            \
        gload_lds16(W2b + (size_t)(wv * 48 + s_ * 16 + srow) * 1152 + (hcv) * 128 + (kc2v) * 32 + scol, \
                    W2w + (buf) * 1536 + s_ * 512 + lane * 8);

    // prologue: A-stripe (6 loads/thread) + W1(0),W1(1)
    #pragma unroll
    for (int k = 0; k < 6; ++k) {
        int l   = tid + 512 * k;
        int kc_ = l >> 8;
        int rem = l & 255;
        gload_lds16(A + (size_t)(m0 + (rem >> 2)) * 384 + kc_ * 32 + (rem & 3) * 8,
                    Ast + l * 8);
    }
    STAGE_W1(0, 0, 0)
    STAGE_W1(0, 1, 1)
    asm volatile("s_waitcnt vmcnt(2)" ::: "memory");   // A complete
    __builtin_amdgcn_sched_barrier(0);
    __builtin_amdgcn_s_barrier();
    __builtin_amdgcn_sched_barrier(0);

    floatx4 acc1[4];
    for (int hc = 0; hc < 9; ++hc) {
        #pragma unroll
        for (int i = 0; i < 4; ++i) acc1[i] = (floatx4)(0.f);

        // --- GEMM1: 12 K-chunks over D=384 ---
        #pragma unroll
        for (int kc = 0; kc < 12; ++kc) {
            if (kc < 10)      { STAGE_W1(hc, kc + 2, (kc + 2) % 3) }
            else if (kc == 10){ STAGE_W2(hc, 0, 0) }
            else              { STAGE_W2(hc, 1, 1) }
            if (kc < 10)       asm volatile("s_waitcnt vmcnt(2)" ::: "memory");
            else if (kc == 10) asm volatile("s_waitcnt vmcnt(4)" ::: "memory");
            else               asm volatile("s_waitcnt vmcnt(6)" ::: "memory");
            short8 afr[4], bfr;
            #pragma unroll
            for (int i = 0; i < 4; ++i)
                afr[i] = *(const short8*)(Ast + kc * 2048 +
                                          (i * 16 + lrow) * 32 + quad * 8);
            bfr = *(const short8*)(W1w + (kc % 3) * 512 + lrow * 32 + quad * 8);
            #pragma unroll
            for (int i = 0; i < 4; ++i)
                acc1[i] = __builtin_amdgcn_mfma_f32_16x16x32_bf16(
                    afr[i], bfr, acc1[i], 0, 0, 0);
        }

        // relu + bf16 + write hblk slice (cols wv*16..+16)
        #pragma unroll
        for (int i = 0; i < 4; ++i)
            #pragma unroll
            for (int r = 0; r < 4; ++r) {
                int row = i * 16 + quad * 4 + r;
                Hs[(wv >> 1) * 2048 + row * 32 + (wv & 1) * 16 + lrow] =
                    f2bf(fmaxf(acc1[i][r], 0.f));
            }
        asm volatile("s_waitcnt lgkmcnt(0)" ::: "memory");
        __builtin_amdgcn_sched_barrier(0);
        __builtin_amdgcn_s_barrier();
        __builtin_amdgcn_sched_barrier(0);

        // --- GEMM2: 4 K-chunks over this hidden block ---
        #pragma unroll
        for (int kc2 = 0; kc2 < 4; ++kc2) {
            if (kc2 == 0)      asm volatile("s_waitcnt vmcnt(3)" ::: "memory");
            else if (kc2 == 1) asm volatile("s_waitcnt vmcnt(4)" ::: "memory");
            else if (kc2 == 2) asm volatile("s_waitcnt vmcnt(5)" ::: "memory");
            else               asm volatile("s_waitcnt vmcnt(1)" ::: "memory");
            short8 afr[4], bfr[3];
            #pragma unroll
            for (int i = 0; i < 4; ++i)
                afr[i] = *(const short8*)(Hs + kc2 * 2048 +
                                          (i * 16 + lrow) * 32 + quad * 8);
            #pragma unroll
            for (int j = 0; j < 3; ++j)
                bfr[j] = *(const short8*)(W2w + (kc2 & 1) * 1536 +
                                          (j * 16 + lrow) * 32 + quad * 8);
            asm volatile("s_waitcnt lgkmcnt(0)" ::: "memory");
            __builtin_amdgcn_sched_barrier(0);
            if (kc2 == 0)      { STAGE_W2(hc, 2, 0) STAGE_W1(hc + 1, 0, 0) }
            else if (kc2 == 1) { STAGE_W2(hc, 3, 1) STAGE_W1(hc + 1, 1, 1) }
            #pragma unroll
            for (int i = 0; i < 4; ++i)
                #pragma unroll
                for (int j = 0; j < 3; ++j)
                    acc2[i][j] = __builtin_amdgcn_mfma_f32_16x16x32_bf16(
                        afr[i], bfr[j], acc2[i][j], 0, 0, 0);
        }
        asm volatile("s_waitcnt lgkmcnt(0)" ::: "memory");
        __builtin_amdgcn_sched_barrier(0);
        __builtin_amdgcn_s_barrier();       // hblk WAR for next hc
        __builtin_amdgcn_sched_barrier(0);
    }
    asm volatile("s_waitcnt vmcnt(0)" ::: "memory");   // drain stale prefetch
#undef STAGE_W1
#undef STAGE_W2

    // --- epilogue: residual(q1_f fp32) + LN2 + transposed write (as FFN2) ---
    float s1[16], s2[16];
    #pragma unroll
    for (int k = 0; k < 16; ++k) { s1[k] = 0.f; s2[k] = 0.f; }
    #pragma unroll
    for (int i = 0; i < 4; ++i) {
        #pragma unroll
        for (int r = 0; r < 4; ++r) {
            int rl = i * 16 + quad * 4 + r;
            #pragma unroll
            for (int j = 0; j < 3; ++j) {
                int col = wv * 48 + j * 16 + lrow;
                float t = acc2[i][j][r];
                t += resid[(size_t)(m0 + rl) * Dc + col];
                acc2[i][j][r] = t;
                s1[i * 4 + r] += t;
                s2[i * 4 + r] += t * t;
            }
        }
    }
    #pragma unroll
    for (int mm = 1; mm < 16; mm <<= 1) {
        #pragma unroll
        for (int k = 0; k < 16; ++k) {
            s1[k] += __shfl_xor(s1[k], mm);
            s2[k] += __shfl_xor(s2[k], mm);
        }
    }
    if (lrow == 0) {
        #pragma unroll
        for (int i = 0; i < 4; ++i)
            #pragma unroll
            for (int r = 0; r < 4; ++r) {
                int rl = i * 16 + quad * 4 + r;
                eps1[wv][rl] = s1[i * 4 + r];
                eps2[wv][rl] = s2[i * 4 + r];
            }
    }
    __syncthreads();
    if (tid < 64) {
        float a1 = 0.f, a2 = 0.f;
        #pragma unroll
        for (int w = 0; w < 8; ++w) { a1 += eps1[w][tid]; a2 += eps2[w][tid]; }
        float mu  = a1 * (1.0f / Dc);
        float var = a2 * (1.0f / Dc) - mu * mu;
        mu_l[tid] = mu;
        rs_l[tid] = rsqrtf(var + 1e-5f);
    }
    __syncthreads();
    #pragma unroll
    for (int i = 0; i < 4; ++i) {
        #pragma unroll
        for (int r = 0; r < 4; ++r) {
            int rl = i * 16 + quad * 4 + r;
            float mu = mu_l[rl], rs = rs_l[rl];
            #pragma unroll
            for (int j = 0; j < 3; ++j) {
                int col = wv * 48 + j * 16 + lrow;
                acc2[i][j][r] = (acc2[i][j][r] - mu) * rs * g[col] + beta[col];
            }
        }
    }
    // transposed write via LDS tile (64 rows x 192 cols, stride 193)
    float* tile = (float*)smem;
    const int b   = m0 >> 12;
    const int n0r = m0 & 4095;
    #pragma unroll
    for (int gp = 0; gp < 2; ++gp) {
        __syncthreads();
        if ((wv >> 2) == gp) {
            int cbase = (wv & 3) * 48;
            #pragma unroll
            for (int i = 0; i < 4; ++i)
                #pragma unroll
                for (int j = 0; j < 3; ++j) {
                    int c = cbase + j * 16 + lrow;
                    #pragma unroll
                    for (int r = 0; r < 4; ++r) {
                        int rl = i * 16 + quad * 4 + r;
                        tile[rl * 193 + c] = acc2[i][j][r];
                    }
                }
        }
        __syncthreads();
        const int row = tid & 63;
        const int cp  = tid >> 6;         // 0..7
        #pragma unroll
        for (int it = 0; it < 24; ++it) {
            int c = it * 8 + cp;
            outf[((size_t)(b * Dc + gp * 192 + c)) * Nc + n0r + row] =
                tile[row * 193 + c];
        }
    }
}

// ---------------------------------------------------------------------------
// K4: deformable attention gather (softmax fused, slice-major).
// ---------------------------------------------------------------------------
__global__ __launch_bounds__(256) void deform_attn_kernel(
        const ushort* __restrict__ value_bf, const float* __restrict__ soaw,
        ushort* __restrict__ out) {
    int bid   = blockIdx.x;                            // 0..3071 = 64 chunks * 48 slices
    int slice = bid % 48;                              // b*M + m  (same-XCD per slice)
    int h     = bid / 48;                              // image row
    int m  = slice % Mc;
    int b  = slice / Mc;
    int w  = threadIdx.x >> 2;                         // 0..63 (column)
    int l4 = threadIdx.x & 3;                          // channel octet
    int n  = (h << 6) | w;
    int bn = b * Nc + n;
    const float* sop = soaw + (size_t)bn * 384 + m * 18;
    const float* lgt = soaw + (size_t)bn * 384 + 216 + m * Pc;
    float awv[Pc];
    float mx = lgt[0];
    #pragma unroll
    for (int i = 1; i < Pc; ++i) mx = fmaxf(mx, lgt[i]);
    float ssum = 0.f;
    #pragma unroll
    for (int i = 0; i < Pc; ++i) { awv[i] = __expf(lgt[i] - mx); ssum += awv[i]; }
    float sinv = 1.f / ssum;
    const ushort* vb = value_bf + ((size_t)b * Nc) * Dc + m * DHc + l4 * 8;
    float acc[8] = {0.f, 0.f, 0.f, 0.f, 0.f, 0.f, 0.f, 0.f};
    #pragma unroll
    for (int p = 0; p < Pc; ++p) {
        float2 so2 = *(const float2*)(sop + p * 2);
        float px = (float)w + so2.x;
        float py = (float)h + so2.y;
        float x0f = floorf(px), y0f = floorf(py);
        float lx = px - x0f, ly = py - y0f;
        int x0 = (int)x0f, y0 = (int)y0f;
        int x1 = x0 + 1,  y1 = y0 + 1;
        float a = awv[p] * sinv;
        float w00 = (1.f - lx) * (1.f - ly) * a;
        float w01 = lx * (1.f - ly) * a;
        float w10 = (1.f - lx) * ly * a;
        float w11 = lx * ly * a;
        bool bx0 = (unsigned)x0 < 64u, bx1 = (unsigned)x1 < 64u;
        bool by0 = (unsigned)y0 < 64u, by1 = (unsigned)y1 < 64u;
        w00 = (bx0 && by0) ? w00 : 0.f;
        w01 = (bx1 && by0) ? w01 : 0.f;
        w10 = (bx0 && by1) ? w10 : 0.f;
        w11 = (bx1 && by1) ? w11 : 0.f;
        int cx0 = min(max(x0, 0), 63), cx1 = min(max(x1, 0), 63);
        int cy0 = min(max(y0, 0), 63), cy1 = min(max(y1, 0), 63);
        uint4 q00 = *(const uint4*)(vb + (size_t)(cy0 * 64 + cx0) * Dc);
        uint4 q01 = *(const uint4*)(vb + (size_t)(cy0 * 64 + cx1) * Dc);
        uint4 q10 = *(const uint4*)(vb + (size_t)(cy1 * 64 + cx0) * Dc);
        uint4 q11 = *(const uint4*)(vb + (size_t)(cy1 * 64 + cx1) * Dc);
        union { unsigned u; float f; } t;
        #define ACC2(word, wg, k)                                   \
            t.u = (word) << 16;         acc[k]     += (wg) * t.f;   \
            t.u = (word) & 0xffff0000u; acc[k + 1] += (wg) * t.f;
        #define ACC8(q, wg) \
            ACC2((q).x, wg, 0) ACC2((q).y, wg, 2) ACC2((q).z, wg, 4) ACC2((q).w, wg, 6)
        ACC8(q00, w00) ACC8(q01, w01) ACC8(q10, w10) ACC8(q11, w11)
        #undef ACC8
        #undef ACC2
    }
    short8 o;
    #pragma unroll
    for (int k = 0; k < 8; ++k) o[k] = (short)f2bf(acc[k]);
    *(short8*)(out + (size_t)bn * Dc + m * DHc + l4 * 8) = o;
}

// ---------------------------------------------------------------------------
extern "C" void kernel_launch(void* const* d_in, const int* in_sizes, int n_in,
                              void* d_out, int out_size, void* d_ws, size_t ws_size,
                              hipStream_t stream) {
    (void)in_sizes; (void)n_in; (void)out_size; (void)ws_size;
    const float* x      = (const float*)d_in[0];
    const float* qmask  = (const float*)d_in[1];
    const float* so_w   = (const float*)d_in[2];
    const float* so_b   = (const float*)d_in[3];
    const float* aw_w   = (const float*)d_in[4];
    const float* aw_b   = (const float*)d_in[5];
    const float* vp_w   = (const float*)d_in[6];
    const float* vp_b   = (const float*)d_in[7];
    const float* op_w   = (const float*)d_in[8];
    const float* op_b   = (const float*)d_in[9];
    const float* ln1_g  = (const float*)d_in[10];
    const float* ln1_b  = (const float*)d_in[11];
    const float* w1     = (const float*)d_in[12];
    const float* w2     = (const float*)d_in[13];
    const float* ln2_g  = (const float*)d_in[14];
    const float* ln2_b  = (const float*)d_in[15];
    const float* lvl    = (const float*)d_in[16];
    float* out = (float*)d_out;

    // Workspace:
    float*  ws       = (float*)d_ws;
    float*  q1_f     = ws;                          // 6291456 f (LN1 out / LN2 residual)
    ushort* src_bf   = (ushort*)(q1_f + 6291456);   // 6291456 us
    ushort* qpos_bf  = src_bf + 6291456;            // 6291456 us (qpos->attn->q1_bf)
    ushort* value_bf = qpos_bf + 6291456;           // 6291456 us
    ushort* hbuf_bf  = value_bf + 6291456;          // 18874368 us (soaw overlay region)
    float*  soaw_f   = (float*)hbuf_bf;             // 6291456 f overlay
    ushort* wbuf     = hbuf_bf + 18874368;          // 1304064 us
    float*  soaw_bias= (float*)(wbuf + 1304064);    // 384 f (padded)
    float*  cum_y    = soaw_bias + 384;             // 16384 f
    float*  cum_x    = cum_y + 16384;               // 16384 f

    const ushort* soaw_wb = wbuf;                   // [324,384] (so_w ++ aw_w)
    const ushort* vp_wb = soaw_wb + SOW_N + AWW_N;
    const ushort* op_wb = vp_wb + VPW_N;
    const ushort* w1_b  = op_wb + OPW_N;
    const ushort* w2_b  = w1_b + W1_N;

    // 0) fused init (weights + bias)
    init_kernel<<<(WTOT + 384 + 255) / 256, 256, 0, stream>>>(
        so_w, aw_w, vp_w, op_w, w1, w2, so_b, aw_b, wbuf, soaw_bias);
    // 0b) mask cumsums via LDS scan
    cumsum_kernel<<<Bc, 256, 0, stream>>>(qmask, cum_y, cum_x);
    // 1) transpose + pos encode
    transpose_pos_kernel<<<dim3(Nc / 32, Dc / 32, Bc), dim3(32, 32), 0, stream>>>(
        x, cum_y, cum_x, lvl, src_bf, qpos_bf);
    // 2) DUAL: z=0 soaw projection (fp32 out), z=1 value projection (bf16+mask)
    gemm_dual_kernel<<<dim3(BNc / 128, 3, 2), 256, 0, stream>>>(
        qpos_bf, soaw_wb, soaw_bias, soaw_f,
        src_bf, vp_wb, vp_b, value_bf, qmask);
    // 3) deformable gather (softmax fused, slice-major) -> attn into qpos_bf
    deform_attn_kernel<<<3072, 256, 0, stream>>>(
        value_bf, soaw_f, qpos_bf);
    // 4) fused op-proj + residual(src_bf) + LN1 -> q1_f + q1_bf (in qpos_bf)
    gemm_fullrow_kernel<384><<<BNc / 64, 512, 0, stream>>>(
        qpos_bf, op_wb, op_b, src_bf, ln1_g, ln1_b, q1_f, qpos_bf);
    // 5) FUSED FFN1+FFN2 + residual(q1_f) + LN2 + transpose -> out[B,D,N]
    ffn_fused_kernel<<<BNc / 64, 512, 0, stream>>>(
        qpos_bf, w1_b, w2_b, q1_f, ln2_g, ln2_b, out);
}

// Round 7
// 254.244 us; speedup vs baseline: 1.2563x; 1.0204x over previous
//
#include <hip/hip_runtime.h>
#include <math.h>

// Problem constants
#define Bc   4
#define Hc   64
#define Wc   64
#define Dc   384
#define Nc   4096      // H*W
#define Mc   12
#define Pc   9
#define DHc  32
#define DFFc 1152
#define BNc  (Bc*Nc)   // 16384

typedef __attribute__((ext_vector_type(8))) short short8;
typedef __attribute__((ext_vector_type(4))) short short4v;
typedef __attribute__((ext_vector_type(4))) float floatx4;

__device__ __forceinline__ ushort f2bf(float f) {
    union { float f; unsigned u; } v; v.f = f;
    unsigned r = v.u + 0x7fffu + ((v.u >> 16) & 1u);   // RNE
    return (ushort)(r >> 16);
}
__device__ __forceinline__ float bf2f(ushort u) {
    union { unsigned u; float f; } v; v.u = (unsigned)u << 16; return v.f;
}

__device__ __forceinline__ void gload_lds16(const void* g, void* l) {
    __builtin_amdgcn_global_load_lds(
        (const __attribute__((address_space(1))) void*)(uintptr_t)g,
        (__attribute__((address_space(3))) void*)(uintptr_t)l,
        16, 0, 0);
}

// ---------------------------------------------------------------------------
// K0: fused init — weight fp32->bf16 convert, bias concat.
// ---------------------------------------------------------------------------
#define SOW_N  82944     // 216*384
#define AWW_N  41472     // 108*384
#define VPW_N  147456    // 384*384
#define OPW_N  147456
#define W1_N   442368    // 1152*384
#define W2_N   442368    // 384*1152
#define WTOT   1304064

__global__ void init_kernel(const float* __restrict__ so_w,
                            const float* __restrict__ aw_w,
                            const float* __restrict__ vp_w,
                            const float* __restrict__ op_w,
                            const float* __restrict__ w1,
                            const float* __restrict__ w2,
                            const float* __restrict__ so_b,
                            const float* __restrict__ aw_b,
                            ushort* __restrict__ out,
                            float* __restrict__ bias_out) {
    int i = blockIdx.x * 256 + threadIdx.x;
    if (i < WTOT) {
        float v;
        int j = i;
        if (j < SOW_N) v = so_w[j];
        else if ((j -= SOW_N) < AWW_N) v = aw_w[j];
        else if ((j -= AWW_N) < VPW_N) v = vp_w[j];
        else if ((j -= VPW_N) < OPW_N) v = op_w[j];
        else if ((j -= OPW_N) < W1_N)  v = w1[j];
        else { j -= W1_N; v = w2[j]; }
        out[i] = f2bf(v);
        return;
    }
    int j = i - WTOT;
    if (j < 384) {   // pad bias to 384 with zeros (col-tile over-read safety)
        bias_out[j] = (j < 216) ? so_b[j] : (j < 324 ? aw_b[j - 216] : 0.f);
    }
}

// ---------------------------------------------------------------------------
// K0b: mask cumsums via LDS (coalesced loads/stores, scans over LDS).
// ---------------------------------------------------------------------------
__global__ __launch_bounds__(256) void cumsum_kernel(
        const float* __restrict__ qmask,
        float* __restrict__ cum_y, float* __restrict__ cum_x) {
    __shared__ float nm[64 * 65];     // stride 65: conflict-free rows AND cols
    __shared__ float ot[64 * 65];
    int b = blockIdx.x;
    int t = threadIdx.x;
    const float* qm = qmask + b * 4096;
    #pragma unroll
    for (int k = 0; k < 16; ++k) {
        int idx = t + k * 256;
        nm[(idx >> 6) * 65 + (idx & 63)] = (qm[idx] == 255.0f) ? 0.f : 1.f;
    }
    __syncthreads();
    if (t < 64) {                     // column scan over h (cum_y), t = w
        float run = 0.f;
        for (int h = 0; h < 64; ++h) { run += nm[h * 65 + t]; ot[h * 65 + t] = run; }
    }
    __syncthreads();
    #pragma unroll
    for (int k = 0; k < 16; ++k) {
        int idx = t + k * 256;
        cum_y[b * 4096 + idx] = ot[(idx >> 6) * 65 + (idx & 63)];
    }
    __syncthreads();
    if (t < 64) {                     // row scan over w (cum_x), t = h
        float run = 0.f;
        for (int w = 0; w < 64; ++w) { run += nm[t * 65 + w]; ot[t * 65 + w] = run; }
    }
    __syncthreads();
    #pragma unroll
    for (int k = 0; k < 16; ++k) {
        int idx = t + k * 256;
        cum_x[b * 4096 + idx] = ot[(idx >> 6) * 65 + (idx & 63)];
    }
}

// ---------------------------------------------------------------------------
// K1: transpose x[B,D,N] -> src_bf[B,N,D] (bf16);
//     qpos_bf = bf16(src + sine_pos + level_embed). Fast-math trig.
// ---------------------------------------------------------------------------
__global__ void transpose_pos_kernel(const float* __restrict__ x,
                                     const float* __restrict__ cum_y,
                                     const float* __restrict__ cum_x,
                                     const float* __restrict__ level_embed,
                                     ushort* __restrict__ src_bf,
                                     ushort* __restrict__ qpos_bf) {
    __shared__ float tile[32][33];
    int b  = blockIdx.z;
    int n0 = blockIdx.x * 32, d0 = blockIdx.y * 32;
    int tx = threadIdx.x, ty = threadIdx.y;
    tile[ty][tx] = x[((size_t)b * Dc + (d0 + ty)) * Nc + (n0 + tx)];
    __syncthreads();
    int n = n0 + ty, d = d0 + tx;
    float v = tile[tx][ty];
    size_t oi = ((size_t)b * Nc + n) * Dc + d;
    src_bf[oi] = f2bf(v);
    int h = n >> 6, w = n & 63;
    const float TWO_PI = 6.28318530717958647692f;
    float vy = cum_y[(b * Hc + h) * Wc + w] /
               (cum_y[(b * Hc + (Hc - 1)) * Wc + w] + 1e-6f) * TWO_PI;
    float vx = cum_x[(b * Hc + h) * Wc + w] /
               (cum_x[(b * Hc + h) * Wc + (Wc - 1)] + 1e-6f) * TWO_PI;
    int   i  = (d < 192) ? d : d - 192;
    float vv = (d < 192) ? vy : vx;
    float e   = (float)(i >> 1) * (2.0f / 192.0f);
    float idt = exp2f(e * -13.28771237954945f);
    float ang = vv * idt;
    float pe  = (i & 1) ? __cosf(ang) : __sinf(ang);
    qpos_bf[oi] = f2bf(v + pe + level_embed[d]);
}

// ---------------------------------------------------------------------------
// K2: bf16 MFMA GEMM core: 128x128 tile, global_load_lds, double-buffered
//     LDS, one barrier/K-chunk (used by the dual projection kernel).
// ---------------------------------------------------------------------------
template <int KT>
__device__ __forceinline__ void gemm_core(
        const ushort* __restrict__ A, const ushort* __restrict__ Wt,
        const float* __restrict__ bias,
        float* __restrict__ Cf, ushort* __restrict__ Cb,
        int Nout, int relu, const float* __restrict__ qmask,
        ushort* As, ushort* Bs) {           // As/Bs: 2 x 128*32 each
    constexpr int NCH = KT / 32;
    const int tid  = threadIdx.x;
    const int m0   = blockIdx.x * 128;
    const int n0   = blockIdx.y * 128;
    const int lane = tid & 63;
    const int wv   = tid >> 6;
    const int wr   = (wv >> 1) * 64;
    const int wc   = (wv & 1) * 64;
    const int quad = lane >> 4;
    const int lrow = lane & 15;
    const int srow = wv * 32 + (lane >> 2);
    const int scol = (lane & 3) * 8;

    floatx4 acc[4][4];
    #pragma unroll
    for (int i = 0; i < 4; ++i)
        #pragma unroll
        for (int j = 0; j < 4; ++j)
            acc[i][j] = (floatx4)(0.f);

    #pragma unroll
    for (int s = 0; s < 2; ++s) {
        gload_lds16(A  + (size_t)(m0 + srow + s * 16) * KT + scol,
                    As + wv * 1024 + s * 512);
        gload_lds16(Wt + (size_t)(n0 + srow + s * 16) * KT + scol,
                    Bs + wv * 1024 + s * 512);
    }

    for (int c = 0; c < NCH; ++c) {
        const int cur = c & 1;
        __syncthreads();
        if (c + 1 < NCH) {
            const int k0 = (c + 1) * 32;
            #pragma unroll
            for (int s = 0; s < 2; ++s) {
                gload_lds16(A  + (size_t)(m0 + srow + s * 16) * KT + k0 + scol,
                            As + (cur ^ 1) * 4096 + wv * 1024 + s * 512);
                gload_lds16(Wt + (size_t)(n0 + srow + s * 16) * KT + k0 + scol,
                            Bs + (cur ^ 1) * 4096 + wv * 1024 + s * 512);
            }
        }
        short8 afr[4], bfr[4];
        #pragma unroll
        for (int i = 0; i < 4; ++i)
            afr[i] = *(const short8*)(As + cur * 4096 +
                                      (wr + i * 16 + lrow) * 32 + quad * 8);
        #pragma unroll
        for (int j = 0; j < 4; ++j)
            bfr[j] = *(const short8*)(Bs + cur * 4096 +
                                      (wc + j * 16 + lrow) * 32 + quad * 8);
        #pragma unroll
        for (int i = 0; i < 4; ++i)
            #pragma unroll
            for (int j = 0; j < 4; ++j)
                acc[i][j] = __builtin_amdgcn_mfma_f32_16x16x32_bf16(
                    afr[i], bfr[j], acc[i][j], 0, 0, 0);
    }

    float mz[4][4];
    #pragma unroll
    for (int i = 0; i < 4; ++i)
        #pragma unroll
        for (int r = 0; r < 4; ++r) {
            int row = m0 + wr + i * 16 + quad * 4 + r;
            mz[i][r] = (qmask && qmask[row] == 255.0f) ? 0.f : 1.f;
        }

    #pragma unroll
    for (int i = 0; i < 4; ++i) {
        #pragma unroll
        for (int j = 0; j < 4; ++j) {
            int col = n0 + wc + j * 16 + lrow;
            if (col >= Nout) continue;
            float bsv = bias ? bias[col] : 0.f;
            #pragma unroll
            for (int r = 0; r < 4; ++r) {
                int row = m0 + wr + i * 16 + quad * 4 + r;
                float v = acc[i][j][r] + bsv;
                if (relu) v = fmaxf(v, 0.f);
                v *= mz[i][r];
                if (Cf) Cf[(size_t)row * Nout + col] = v;
                if (Cb) Cb[(size_t)row * Nout + col] = f2bf(v);
            }
        }
    }
}

// dual dispatch: z=0 -> soaw projection, z=1 -> value projection (overlapped)
__global__ __launch_bounds__(256) void gemm_dual_kernel(
        const ushort* __restrict__ A0, const ushort* __restrict__ W0,
        const float* __restrict__ b0, float* __restrict__ Cf0,
        const ushort* __restrict__ A1, const ushort* __restrict__ W1,
        const float* __restrict__ b1, ushort* __restrict__ Cb1,
        const float* __restrict__ qmask) {
    __shared__ ushort As[2 * 128 * 32];
    __shared__ ushort Bs[2 * 128 * 32];
    if (blockIdx.z == 0)
        gemm_core<384>(A0, W0, b0, Cf0, nullptr, 384, 0, nullptr, As, Bs);
    else
        gemm_core<384>(A1, W1, b1, nullptr, Cb1, 384, 0, qmask, As, Bs);
}

// ---------------------------------------------------------------------------
// K3: full-row GEMM + LayerNorm fusion (LN1) — R5-verified counted-vmcnt:
//     64-row stripe, 512 threads, grid 256, 4-buffer LDS, staged 3 ahead,
//     raw s_barrier (no drain) per chunk. Residual bf16, writes q1_f + q1_bf.
// ---------------------------------------------------------------------------
template <int KT>
__global__ __launch_bounds__(512) void gemm_fullrow_kernel(
        const ushort* __restrict__ A, const ushort* __restrict__ Wt,
        const float* __restrict__ bias, const void* __restrict__ resid,
        const float* __restrict__ g, const float* __restrict__ beta,
        float* __restrict__ outf, ushort* __restrict__ outb) {
    constexpr int NCH = KT / 32;
    __shared__ ushort As[4 * 2048];           // 16KB: 4 bufs x 64x32
    __shared__ ushort Bs[4 * 12288];          // 96KB: 4 bufs x 384x32
    __shared__ float eps1[8][64], eps2[8][64];
    __shared__ float mu_l[64], rs_l[64];
    const int tid  = threadIdx.x;
    const int lane = tid & 63;
    const int wv   = tid >> 6;                // 0..7
    const int quad = lane >> 4;
    const int lrow = lane & 15;
    const int m0   = blockIdx.x * 64;
    const int srow = lane >> 2;               // 0..15
    const int scol = (lane & 3) * 8;

    floatx4 acc[4][3];
    #pragma unroll
    for (int i = 0; i < 4; ++i)
        #pragma unroll
        for (int j = 0; j < 3; ++j)
            acc[i][j] = (floatx4)(0.f);

#define STAGE_CHUNK(c, buf)                                                   \
    {   const int k0_ = (c) * 32;                                             \
        if (wv < 4)                                                           \
            gload_lds16(A + (size_t)(m0 + wv * 16 + srow) * KT + k0_ + scol,  \
                        As + (buf) * 2048 + wv * 512);                        \
        _Pragma("unroll")                                                     \
        for (int s_ = 0; s_ < 3; ++s_)                                        \
            gload_lds16(Wt + (size_t)(wv * 48 + s_ * 16 + srow) * KT + k0_ + scol, \
                        Bs + (buf) * 12288 + wv * 1536 + s_ * 512);           \
    }

    // prologue: stage chunks 0,1,2 -> bufs 0,1,2
    STAGE_CHUNK(0, 0)
    STAGE_CHUNK(1, 1)
    STAGE_CHUNK(2, 2)

    #pragma unroll
    for (int c = 0; c < NCH; ++c) {
        const int rem = (NCH - 1 - c) >= 2 ? 2 : (NCH - 1 - c);
        if (wv < 4) {
            if (rem == 2)      asm volatile("s_waitcnt vmcnt(8)" ::: "memory");
            else if (rem == 1) asm volatile("s_waitcnt vmcnt(4)" ::: "memory");
            else               asm volatile("s_waitcnt vmcnt(0)" ::: "memory");
        } else {
            if (rem == 2)      asm volatile("s_waitcnt vmcnt(6)" ::: "memory");
            else if (rem == 1) asm volatile("s_waitcnt vmcnt(3)" ::: "memory");
            else               asm volatile("s_waitcnt vmcnt(0)" ::: "memory");
        }
        __builtin_amdgcn_s_barrier();
        __builtin_amdgcn_sched_barrier(0);
        if (c + 3 < NCH) { STAGE_CHUNK(c + 3, (c + 3) & 3) }
        const int buf = c & 3;
        short8 afr[4], bfr[3];
        #pragma unroll
        for (int i = 0; i < 4; ++i)
            afr[i] = *(const short8*)(As + buf * 2048 +
                                      (i * 16 + lrow) * 32 + quad * 8);
        #pragma unroll
        for (int j = 0; j < 3; ++j)
            bfr[j] = *(const short8*)(Bs + buf * 12288 +
                                      (wv * 48 + j * 16 + lrow) * 32 + quad * 8);
        #pragma unroll
        for (int i = 0; i < 4; ++i)
            #pragma unroll
            for (int j = 0; j < 3; ++j)
                acc[i][j] = __builtin_amdgcn_mfma_f32_16x16x32_bf16(
                    afr[i], bfr[j], acc[i][j], 0, 0, 0);
    }
#undef STAGE_CHUNK

    // --- epilogue: residual add + row-sum -> LN ---
    float s1[16], s2[16];
    #pragma unroll
    for (int k = 0; k < 16; ++k) { s1[k] = 0.f; s2[k] = 0.f; }
    #pragma unroll
    for (int i = 0; i < 4; ++i) {
        #pragma unroll
        for (int r = 0; r < 4; ++r) {
            int rl = i * 16 + quad * 4 + r;
            #pragma unroll
            for (int j = 0; j < 3; ++j) {
                int col = wv * 48 + j * 16 + lrow;
                float t = acc[i][j][r];
                if (bias) t += bias[col];
                t += bf2f(((const ushort*)resid)[(size_t)(m0 + rl) * Dc + col]);
                acc[i][j][r] = t;
                s1[i * 4 + r] += t;
                s2[i * 4 + r] += t * t;
            }
        }
    }
    #pragma unroll
    for (int mm = 1; mm < 16; mm <<= 1) {
        #pragma unroll
        for (int k = 0; k < 16; ++k) {
            s1[k] += __shfl_xor(s1[k], mm);
            s2[k] += __shfl_xor(s2[k], mm);
        }
    }
    if (lrow == 0) {
        #pragma unroll
        for (int i = 0; i < 4; ++i)
            #pragma unroll
            for (int r = 0; r < 4; ++r) {
                int rl = i * 16 + quad * 4 + r;
                eps1[wv][rl] = s1[i * 4 + r];
                eps2[wv][rl] = s2[i * 4 + r];
            }
    }
    __syncthreads();
    if (tid < 64) {
        float a1 = 0.f, a2 = 0.f;
        #pragma unroll
        for (int w = 0; w < 8; ++w) { a1 += eps1[w][tid]; a2 += eps2[w][tid]; }
        float mu  = a1 * (1.0f / Dc);
        float var = a2 * (1.0f / Dc) - mu * mu;
        mu_l[tid] = mu;
        rs_l[tid] = rsqrtf(var + 1e-5f);
    }
    __syncthreads();
    #pragma unroll
    for (int i = 0; i < 4; ++i) {
        #pragma unroll
        for (int r = 0; r < 4; ++r) {
            int rl = i * 16 + quad * 4 + r;
            float mu = mu_l[rl], rs = rs_l[rl];
            #pragma unroll
            for (int j = 0; j < 3; ++j) {
                int col = wv * 48 + j * 16 + lrow;
                float v = (acc[i][j][r] - mu) * rs * g[col] + beta[col];
                outf[(size_t)(m0 + rl) * Dc + col] = v;
                outb[(size_t)(m0 + rl) * Dc + col] = f2bf(v);
            }
        }
    }
}

// ---------------------------------------------------------------------------
// K5: FUSED FFN (FFN1+relu+FFN2) + residual + LN2 + transposed write.
//     R6-verified structure with two changes:
//     (1) GEMM1 operands SWAPPED: mfma(w1_frag, a_frag) -> lane holds 4
//         CONSECUTIVE hidden values for one m-row (m on lrow, h on quad*4+r;
//         bitwise-identical math, transposed placement). Hs write becomes
//         4 x ds_write_b64 (was 16 x b16 at 8-way conflict), XOR-swizzled:
//         slot' = slot ^ (mrow&6) (bit0 untouched -> GEMM2's b128 reads stay
//         16B-contiguous, read applies the same involution).
//     (2) W1 ring 3->4, depth-3 prefetch. Re-derived wave-private FIFO
//         (16B ops): GEMM1 kc<=8 stage W1(kc+3), wait vmcnt(3); kc=9 stage
//         W2(0) wait (5); kc=10 stage W2(1) wait (7); kc=11 wait (6).
//         GEMM2 kc2=0..3: wait 3/4/5/2; stage W2(2)+W1'(0), W2(3)+W1'(1),
//         W1'(2), none. Exit queue [W1'(1),W1'(2)] matches GEMM1 entry.
//     LDS: A 48K + Hs 16K + W1 32K + W2 48K = 144K (+4.5K LN scratch).
// ---------------------------------------------------------------------------
__global__ __launch_bounds__(512) void ffn_fused_kernel(
        const ushort* __restrict__ A,      // q1_bf [BN][384]
        const ushort* __restrict__ W1b,    // [1152][384]
        const ushort* __restrict__ W2b,    // [384][1152]
        const float* __restrict__ resid,   // q1_f
        const float* __restrict__ g, const float* __restrict__ beta,
        float* __restrict__ outf) {
    __shared__ ushort smem[73728];         // 144KB carved below
    ushort* Ast = smem;                    // 12 chunks x [64][32] = 24576
    ushort* Hs  = smem + 24576;            // 4 chunks x [64][32]  = 8192
    ushort* W1s = smem + 32768;            // 8 waves x 4 bufs x 512 = 16384
    ushort* W2s = smem + 49152;            // 8 waves x 2 bufs x 1536 = 24576
    __shared__ float eps1[8][64], eps2[8][64];
    __shared__ float mu_l[64], rs_l[64];

    const int tid  = threadIdx.x;
    const int lane = tid & 63;
    const int wv   = tid >> 6;
    const int quad = lane >> 4;
    const int lrow = lane & 15;
    const int m0   = blockIdx.x * 64;
    const int srow = lane >> 2;
    const int scol = (lane & 3) * 8;

    ushort* W1w = W1s + wv * 2048;         // 4 bufs x 512
    ushort* W2w = W2s + wv * 3072;         // 2 bufs x 1536

    floatx4 acc2[4][3];
    #pragma unroll
    for (int i = 0; i < 4; ++i)
        #pragma unroll
        for (int j = 0; j < 3; ++j)
            acc2[i][j] = (floatx4)(0.f);

#define STAGE_W1(hcv, kcv, buf)                                               \
    gload_lds16(W1b + (size_t)((hcv) * 128 + wv * 16 + srow) * 384 + (kcv) * 32 + scol, \
                W1w + (buf) * 512 + lane * 8);

#define STAGE_W2(hcv, kc2v, buf)                                              \
    _Pragma("unroll")                                                         \
    for (int s_ = 0; s_ < 3; ++s_)                                            \
        gload_lds16(W2b + (size_t)(wv * 48 + s_ * 16 + srow) * 1152 + (hcv) * 128 + (kc2v) * 32 + scol, \
                    W2w + (buf) * 1536 + s_ * 512 + lane * 8);

    // prologue: A-stripe (6 loads/thread) + W1(0),W1(1),W1(2)
    #pragma unroll
    for (int k = 0; k < 6; ++k) {
        int l   = tid + 512 * k;
        int kc_ = l >> 8;
        int rem = l & 255;
        gload_lds16(A + (size_t)(m0 + (rem >> 2)) * 384 + kc_ * 32 + (rem & 3) * 8,
                    Ast + l * 8);
    }
    STAGE_W1(0, 0, 0)
    STAGE_W1(0, 1, 1)
    STAGE_W1(0, 2, 2)
    asm volatile("s_waitcnt vmcnt(3)" ::: "memory");   // A complete
    __builtin_amdgcn_sched_barrier(0);
    __builtin_amdgcn_s_barrier();
    __builtin_amdgcn_sched_barrier(0);

    floatx4 acc1[4];
    for (int hc = 0; hc < 9; ++hc) {
        #pragma unroll
        for (int i = 0; i < 4; ++i) acc1[i] = (floatx4)(0.f);

        // --- GEMM1 (swapped operands): 12 K-chunks over D=384 ---
        #pragma unroll
        for (int kc = 0; kc < 12; ++kc) {
            if (kc <= 8)       { STAGE_W1(hc, kc + 3, (kc + 3) & 3) }
            else if (kc == 9)  { STAGE_W2(hc, 0, 0) }
            else if (kc == 10) { STAGE_W2(hc, 1, 1) }
            if (kc <= 8)       asm volatile("s_waitcnt vmcnt(3)" ::: "memory");
            else if (kc == 9)  asm volatile("s_waitcnt vmcnt(5)" ::: "memory");
            else if (kc == 10) asm volatile("s_waitcnt vmcnt(7)" ::: "memory");
            else               asm volatile("s_waitcnt vmcnt(6)" ::: "memory");
            short8 afr[4], bfr;
            #pragma unroll
            for (int i = 0; i < 4; ++i)
                afr[i] = *(const short8*)(Ast + kc * 2048 +
                                          (i * 16 + lrow) * 32 + quad * 8);
            bfr = *(const short8*)(W1w + (kc & 3) * 512 + lrow * 32 + quad * 8);
            #pragma unroll
            for (int i = 0; i < 4; ++i)
                acc1[i] = __builtin_amdgcn_mfma_f32_16x16x32_bf16(
                    bfr, afr[i], acc1[i], 0, 0, 0);   // SWAPPED: H^T layout
        }

        // relu + bf16 + b64 write (4 consecutive hidden per lane), swizzled
        #pragma unroll
        for (int i = 0; i < 4; ++i) {
            short4v pk;
            #pragma unroll
            for (int r = 0; r < 4; ++r)
                pk[r] = (short)f2bf(fmaxf(acc1[i][r], 0.f));
            int mrow = i * 16 + lrow;
            int slot = ((wv & 1) * 4 + quad) ^ (mrow & 6);
            *(short4v*)(Hs + (wv >> 1) * 2048 + mrow * 32 + slot * 4) = pk;
        }
        asm volatile("s_waitcnt lgkmcnt(0)" ::: "memory");
        __builtin_amdgcn_sched_barrier(0);
        __builtin_amdgcn_s_barrier();
        __builtin_amdgcn_sched_barrier(0);

        // --- GEMM2: 4 K-chunks over this hidden block ---
        #pragma unroll
        for (int kc2 = 0; kc2 < 4; ++kc2) {
            if (kc2 == 0)      asm volatile("s_waitcnt vmcnt(3)" ::: "memory");
            else if (kc2 == 1) asm volatile("s_waitcnt vmcnt(4)" ::: "memory");
            else if (kc2 == 2) asm volatile("s_waitcnt vmcnt(5)" ::: "memory");
            else               asm volatile("s_waitcnt vmcnt(2)" ::: "memory");
            short8 afr[4], bfr[3];
            #pragma unroll
            for (int i = 0; i < 4; ++i) {
                int mrow = i * 16 + lrow;
                int s0 = (quad * 2) ^ (mrow & 6);     // even: b128 stays 16B
                afr[i] = *(const short8*)(Hs + kc2 * 2048 + mrow * 32 + s0 * 4);
            }
            #pragma unroll
            for (int j = 0; j < 3; ++j)
                bfr[j] = *(const short8*)(W2w + (kc2 & 1) * 1536 +
                                          (j * 16 + lrow) * 32 + quad * 8);
            asm volatile("s_waitcnt lgkmcnt(0)" ::: "memory");
            __builtin_amdgcn_sched_barrier(0);
            if (kc2 == 0)      { STAGE_W2(hc, 2, 0) STAGE_W1(hc + 1, 0, 0) }
            else if (kc2 == 1) { STAGE_W2(hc, 3, 1) STAGE_W1(hc + 1, 1, 1) }
            else if (kc2 == 2) { STAGE_W1(hc + 1, 2, 2) }
            #pragma unroll
            for (int i = 0; i < 4; ++i)
                #pragma unroll
                for (int j = 0; j < 3; ++j)
                    acc2[i][j] = __builtin_amdgcn_mfma_f32_16x16x32_bf16(
                        afr[i], bfr[j], acc2[i][j], 0, 0, 0);
        }
        asm volatile("s_waitcnt lgkmcnt(0)" ::: "memory");
        __builtin_amdgcn_sched_barrier(0);
        __builtin_amdgcn_s_barrier();       // hblk WAR for next hc
        __builtin_amdgcn_sched_barrier(0);
    }
    asm volatile("s_waitcnt vmcnt(0)" ::: "memory");   // drain stale prefetch
#undef STAGE_W1
#undef STAGE_W2

    // --- epilogue: residual(q1_f fp32) + LN2 + transposed write ---
    float s1[16], s2[16];
    #pragma unroll
    for (int k = 0; k < 16; ++k) { s1[k] = 0.f; s2[k] = 0.f; }
    #pragma unroll
    for (int i = 0; i < 4; ++i) {
        #pragma unroll
        for (int r = 0; r < 4; ++r) {
            int rl = i * 16 + quad * 4 + r;
            #pragma unroll
            for (int j = 0; j < 3; ++j) {
                int col = wv * 48 + j * 16 + lrow;
                float t = acc2[i][j][r];
                t += resid[(size_t)(m0 + rl) * Dc + col];
                acc2[i][j][r] = t;
                s1[i * 4 + r] += t;
                s2[i * 4 + r] += t * t;
            }
        }
    }
    #pragma unroll
    for (int mm = 1; mm < 16; mm <<= 1) {
        #pragma unroll
        for (int k = 0; k < 16; ++k) {
            s1[k] += __shfl_xor(s1[k], mm);
            s2[k] += __shfl_xor(s2[k], mm);
        }
    }
    if (lrow == 0) {
        #pragma unroll
        for (int i = 0; i < 4; ++i)
            #pragma unroll
            for (int r = 0; r < 4; ++r) {
                int rl = i * 16 + quad * 4 + r;
                eps1[wv][rl] = s1[i * 4 + r];
                eps2[wv][rl] = s2[i * 4 + r];
            }
    }
    __syncthreads();
    if (tid < 64) {
        float a1 = 0.f, a2 = 0.f;
        #pragma unroll
        for (int w = 0; w < 8; ++w) { a1 += eps1[w][tid]; a2 += eps2[w][tid]; }
        float mu  = a1 * (1.0f / Dc);
        float var = a2 * (1.0f / Dc) - mu * mu;
        mu_l[tid] = mu;
        rs_l[tid] = rsqrtf(var + 1e-5f);
    }
    __syncthreads();
    #pragma unroll
    for (int i = 0; i < 4; ++i) {
        #pragma unroll
        for (int r = 0; r < 4; ++r) {
            int rl = i * 16 + quad * 4 + r;
            float mu = mu_l[rl], rs = rs_l[rl];
            #pragma unroll
            for (int j = 0; j < 3; ++j) {
                int col = wv * 48 + j * 16 + lrow;
                acc2[i][j][r] = (acc2[i][j][r] - mu) * rs * g[col] + beta[col];
            }
        }
    }
    // transposed write via LDS tile (64 rows x 192 cols, stride 193)
    float* tile = (float*)smem;
    const int b   = m0 >> 12;
    const int n0r = m0 & 4095;
    #pragma unroll
    for (int gp = 0; gp < 2; ++gp) {
        __syncthreads();
        if ((wv >> 2) == gp) {
            int cbase = (wv & 3) * 48;
            #pragma unroll
            for (int i = 0; i < 4; ++i)
                #pragma unroll
                for (int j = 0; j < 3; ++j) {
                    int c = cbase + j * 16 + lrow;
                    #pragma unroll
                    for (int r = 0; r < 4; ++r) {
                        int rl = i * 16 + quad * 4 + r;
                        tile[rl * 193 + c] = acc2[i][j][r];
                    }
                }
        }
        __syncthreads();
        const int row = tid & 63;
        const int cp  = tid >> 6;         // 0..7
        #pragma unroll
        for (int it = 0; it < 24; ++it) {
            int c = it * 8 + cp;
            outf[((size_t)(b * Dc + gp * 192 + c)) * Nc + n0r + row] =
                tile[row * 193 + c];
        }
    }
}

// ---------------------------------------------------------------------------
// K4: deformable attention gather (softmax fused, slice-major).
// ---------------------------------------------------------------------------
__global__ __launch_bounds__(256) void deform_attn_kernel(
        const ushort* __restrict__ value_bf, const float* __restrict__ soaw,
        ushort* __restrict__ out) {
    int bid   = blockIdx.x;                            // 0..3071 = 64 chunks * 48 slices
    int slice = bid % 48;                              // b*M + m  (same-XCD per slice)
    int h     = bid / 48;                              // image row
    int m  = slice % Mc;
    int b  = slice / Mc;
    int w  = threadIdx.x >> 2;                         // 0..63 (column)
    int l4 = threadIdx.x & 3;                          // channel octet
    int n  = (h << 6) | w;
    int bn = b * Nc + n;
    const float* sop = soaw + (size_t)bn * 384 + m * 18;
    const float* lgt = soaw + (size_t)bn * 384 + 216 + m * Pc;
    float awv[Pc];
    float mx = lgt[0];
    #pragma unroll
    for (int i = 1; i < Pc; ++i) mx = fmaxf(mx, lgt[i]);
    float ssum = 0.f;
    #pragma unroll
    for (int i = 0; i < Pc; ++i) { awv[i] = __expf(lgt[i] - mx); ssum += awv[i]; }
    float sinv = 1.f / ssum;
    const ushort* vb = value_bf + ((size_t)b * Nc) * Dc + m * DHc + l4 * 8;
    float acc[8] = {0.f, 0.f, 0.f, 0.f, 0.f, 0.f, 0.f, 0.f};
    #pragma unroll
    for (int p = 0; p < Pc; ++p) {
        float2 so2 = *(const float2*)(sop + p * 2);
        float px = (float)w + so2.x;
        float py = (float)h + so2.y;
        float x0f = floorf(px), y0f = floorf(py);
        float lx = px - x0f, ly = py - y0f;
        int x0 = (int)x0f, y0 = (int)y0f;
        int x1 = x0 + 1,  y1 = y0 + 1;
        float a = awv[p] * sinv;
        float w00 = (1.f - lx) * (1.f - ly) * a;
        float w01 = lx * (1.f - ly) * a;
        float w10 = (1.f - lx) * ly * a;
        float w11 = lx * ly * a;
        bool bx0 = (unsigned)x0 < 64u, bx1 = (unsigned)x1 < 64u;
        bool by0 = (unsigned)y0 < 64u, by1 = (unsigned)y1 < 64u;
        w00 = (bx0 && by0) ? w00 : 0.f;
        w01 = (bx1 && by0) ? w01 : 0.f;
        w10 = (bx0 && by1) ? w10 : 0.f;
        w11 = (bx1 && by1) ? w11 : 0.f;
        int cx0 = min(max(x0, 0), 63), cx1 = min(max(x1, 0), 63);
        int cy0 = min(max(y0, 0), 63), cy1 = min(max(y1, 0), 63);
        uint4 q00 = *(const uint4*)(vb + (size_t)(cy0 * 64 + cx0) * Dc);
        uint4 q01 = *(const uint4*)(vb + (size_t)(cy0 * 64 + cx1) * Dc);
        uint4 q10 = *(const uint4*)(vb + (size_t)(cy1 * 64 + cx0) * Dc);
        uint4 q11 = *(const uint4*)(vb + (size_t)(cy1 * 64 + cx1) * Dc);
        union { unsigned u; float f; } t;
        #define ACC2(word, wg, k)                                   \
            t.u = (word) << 16;         acc[k]     += (wg) * t.f;   \
            t.u = (word) & 0xffff0000u; acc[k + 1] += (wg) * t.f;
        #define ACC8(q, wg) \
            ACC2((q).x, wg, 0) ACC2((q).y, wg, 2) ACC2((q).z, wg, 4) ACC2((q).w, wg, 6)
        ACC8(q00, w00) ACC8(q01, w01) ACC8(q10, w10) ACC8(q11, w11)
        #undef ACC8
        #undef ACC2
    }
    short8 o;
    #pragma unroll
    for (int k = 0; k < 8; ++k) o[k] = (short)f2bf(acc[k]);
    *(short8*)(out + (size_t)bn * Dc + m * DHc + l4 * 8) = o;
}

// ---------------------------------------------------------------------------
extern "C" void kernel_launch(void* const* d_in, const int* in_sizes, int n_in,
                              void* d_out, int out_size, void* d_ws, size_t ws_size,
                              hipStream_t stream) {
    (void)in_sizes; (void)n_in; (void)out_size; (void)ws_size;
    const float* x      = (const float*)d_in[0];
    const float* qmask  = (const float*)d_in[1];
    const float* so_w   = (const float*)d_in[2];
    const float* so_b   = (const float*)d_in[3];
    const float* aw_w   = (const float*)d_in[4];
    const float* aw_b   = (const float*)d_in[5];
    const float* vp_w   = (const float*)d_in[6];
    const float* vp_b   = (const float*)d_in[7];
    const float* op_w   = (const float*)d_in[8];
    const float* op_b   = (const float*)d_in[9];
    const float* ln1_g  = (const float*)d_in[10];
    const float* ln1_b  = (const float*)d_in[11];
    const float* w1     = (const float*)d_in[12];
    const float* w2     = (const float*)d_in[13];
    const float* ln2_g  = (const float*)d_in[14];
    const float* ln2_b  = (const float*)d_in[15];
    const float* lvl    = (const float*)d_in[16];
    float* out = (float*)d_out;

    // Workspace:
    float*  ws       = (float*)d_ws;
    float*  q1_f     = ws;                          // 6291456 f (LN1 out / LN2 residual)
    ushort* src_bf   = (ushort*)(q1_f + 6291456);   // 6291456 us
    ushort* qpos_bf  = src_bf + 6291456;            // 6291456 us (qpos->attn->q1_bf)
    ushort* value_bf = qpos_bf + 6291456;           // 6291456 us
    ushort* hbuf_bf  = value_bf + 6291456;          // 18874368 us (soaw overlay region)
    float*  soaw_f   = (float*)hbuf_bf;             // 6291456 f overlay
    ushort* wbuf     = hbuf_bf + 18874368;          // 1304064 us
    float*  soaw_bias= (float*)(wbuf + 1304064);    // 384 f (padded)
    float*  cum_y    = soaw_bias + 384;             // 16384 f
    float*  cum_x    = cum_y + 16384;               // 16384 f

    const ushort* soaw_wb = wbuf;                   // [324,384] (so_w ++ aw_w)
    const ushort* vp_wb = soaw_wb + SOW_N + AWW_N;
    const ushort* op_wb = vp_wb + VPW_N;
    const ushort* w1_b  = op_wb + OPW_N;
    const ushort* w2_b  = w1_b + W1_N;

    // 0) fused init (weights + bias)
    init_kernel<<<(WTOT + 384 + 255) / 256, 256, 0, stream>>>(
        so_w, aw_w, vp_w, op_w, w1, w2, so_b, aw_b, wbuf, soaw_bias);
    // 0b) mask cumsums via LDS scan
    cumsum_kernel<<<Bc, 256, 0, stream>>>(qmask, cum_y, cum_x);
    // 1) transpose + pos encode
    transpose_pos_kernel<<<dim3(Nc / 32, Dc / 32, Bc), dim3(32, 32), 0, stream>>>(
        x, cum_y, cum_x, lvl, src_bf, qpos_bf);
    // 2) DUAL: z=0 soaw projection (fp32 out), z=1 value projection (bf16+mask)
    gemm_dual_kernel<<<dim3(BNc / 128, 3, 2), 256, 0, stream>>>(
        qpos_bf, soaw_wb, soaw_bias, soaw_f,
        src_bf, vp_wb, vp_b, value_bf, qmask);
    // 3) deformable gather (softmax fused, slice-major) -> attn into qpos_bf
    deform_attn_kernel<<<3072, 256, 0, stream>>>(
        value_bf, soaw_f, qpos_bf);
    // 4) fused op-proj + residual(src_bf) + LN1 -> q1_f + q1_bf (in qpos_bf)
    gemm_fullrow_kernel<384><<<BNc / 64, 512, 0, stream>>>(
        qpos_bf, op_wb, op_b, src_bf, ln1_g, ln1_b, q1_f, qpos_bf);
    // 5) FUSED FFN1+FFN2 + residual(q1_f) + LN2 + transpose -> out[B,D,N]
    ffn_fused_kernel<<<BNc / 64, 512, 0, stream>>>(
        qpos_bf, w1_b, w2_b, q1_f, ln2_g, ln2_b, out);
}